// Round 8
// baseline (133.479 us; speedup 1.0000x reference)
//
#include <hip/hip_runtime.h>
#include <hip/hip_bf16.h>

#define BATCH 16
#define CDIM 256
#define NDIM 2048
#define HDIM 128
#define KVB 128
#define NT (NDIM / KVB)

typedef __bf16 bf16;
typedef float f32x4 __attribute__((ext_vector_type(4)));
typedef float f32x16 __attribute__((ext_vector_type(16)));
typedef bf16 bf16x8 __attribute__((ext_vector_type(8)));
typedef unsigned int u32x4 __attribute__((ext_vector_type(4)));
typedef unsigned int u32x2 __attribute__((ext_vector_type(2)));

#define LOG2E 1.4426950408889634f

__device__ __forceinline__ int swz512(int row, int colbyte) {
  return row * 512 + (colbyte ^ ((row & 15) << 4));
}
__device__ __forceinline__ int swz256(int row, int colbyte) {
  return row * 256 + (colbyte ^ ((row & 7) << 4));
}

__device__ __forceinline__ f32x4 mfma16(bf16x8 a, bf16x8 b, f32x4 c) {
  return __builtin_amdgcn_mfma_f32_16x16x32_bf16(a, b, c, 0, 0, 0);
}
__device__ __forceinline__ f32x16 mfma32(bf16x8 a, bf16x8 b, f32x16 c) {
  return __builtin_amdgcn_mfma_f32_32x32x16_bf16(a, b, c, 0, 0, 0);
}

__device__ __forceinline__ unsigned cvtpk(float lo, float hi) {
  unsigned r;
  asm("v_cvt_pk_bf16_f32 %0, %1, %2" : "=v"(r) : "v"(lo), "v"(hi));
  return r;
}
__device__ __forceinline__ void pswap(unsigned &a, unsigned &b) {
  asm volatile("v_permlane32_swap_b32 %0, %1" : "+v"(a), "+v"(b));
}

__device__ __forceinline__ void gload16(const bf16* g, char* l) {
  __builtin_amdgcn_global_load_lds(
      (const __attribute__((address_space(1))) void*)g,
      (__attribute__((address_space(3))) void*)l, 16, 0, 0);
}

__device__ __forceinline__ bf16x8 cvt8(float4 a, float4 b) {
  bf16x8 o;
  o[0] = (bf16)a.x; o[1] = (bf16)a.y; o[2] = (bf16)a.z; o[3] = (bf16)a.w;
  o[4] = (bf16)b.x; o[5] = (bf16)b.y; o[6] = (bf16)b.z; o[7] = (bf16)b.w;
  return o;
}

// ---------------------------------------------------------------------------
// Kernel 0: pack Wq/Wk/Wv into bf16 MFMA-fragment-blocked layout.
// ---------------------------------------------------------------------------
__global__ __launch_bounds__(256) void k0_prep(
    const float* __restrict__ Wq, const float* __restrict__ Wk,
    const float* __restrict__ Wv, bf16* __restrict__ blk) {
  int tg = blockIdx.x * 256 + threadIdx.x;
  int f = tg >> 6, l = tg & 63;
  const float* W = (f < 64) ? Wq : (f < 128 ? Wk : Wv);
  int ks = (f >> 3) & 7, hb = f & 7;
  const float* src = W + (size_t)(hb * 16 + (l & 15)) * CDIM + ks * 32 + (l >> 4) * 8;
  float4 v0 = *reinterpret_cast<const float4*>(src);
  float4 v1 = *reinterpret_cast<const float4*>(src + 4);
  *reinterpret_cast<bf16x8*>(blk + f * 512 + l * 8) = cvt8(v0, v1);
}

// ---------------------------------------------------------------------------
// Kernel 1: fused QKV projection (W direct from L2, shfl-transpose staging,
// one barrier). Q output pre-scaled by LOG2E for k2's exp2-direct softmax.
// ---------------------------------------------------------------------------
__global__ __launch_bounds__(256, 3) void k1_qkv(
    const float* __restrict__ x, const bf16* __restrict__ blk,
    const float* __restrict__ bq, const float* __restrict__ bk,
    const float* __restrict__ bv,
    bf16* __restrict__ Qo, bf16* __restrict__ Ko, bf16* __restrict__ Vo) {
  __shared__ char xT[32768];  // [64 n][256 c] bf16, 512B rows, swz512

  const int t = threadIdx.x;
  const int l = t & 63;
  const int w = t >> 6;
  const int q = (l >> 4) & 3;
  const int b = blockIdx.x >> 5;
  const int n0 = (blockIdx.x & 31) * 64;

#pragma unroll
  for (int p = 0; p < 16; ++p) {
    int c = w * 64 + p * 4 + q;
    float4 v = *reinterpret_cast<const float4*>(
        x + (size_t)(b * CDIM + c) * NDIM + n0 + (l & 15) * 4);
    float t0 = __shfl_xor(v.x, 16), t1 = __shfl_xor(v.y, 16);
    float t2 = __shfl_xor(v.z, 16), t3 = __shfl_xor(v.w, 16);
    float4 wv;
    if ((q & 1) == 0) wv = make_float4(v.x, t0, v.z, t2);
    else              wv = make_float4(t1, v.y, t3, v.w);
    float s0 = __shfl_xor(wv.x, 32), s1 = __shfl_xor(wv.y, 32);
    float s2 = __shfl_xor(wv.z, 32), s3 = __shfl_xor(wv.w, 32);
    float4 z;
    if ((q & 2) == 0) z = make_float4(wv.x, wv.y, s0, s1);
    else              z = make_float4(s2, s3, wv.z, wv.w);
    u32x2 pk = {cvtpk(z.x, z.y), cvtpk(z.z, z.w)};
    int n = (l & 15) * 4 + q;
    int slot = w * 8 + (p >> 1);
    *reinterpret_cast<u32x2*>(
        xT + n * 512 + ((slot ^ (n & 15)) * 16 + (p & 1) * 8)) = pk;
  }
  __syncthreads();

  const bf16* bq_ = blk;
  const bf16* bk_ = blk + 64 * 512;
  const bf16* bv_ = blk + 128 * 512;

  f32x4 aq[8], ak[8], av[8];
#pragma unroll
  for (int i = 0; i < 8; ++i) {
    aq[i] = f32x4{0.f, 0.f, 0.f, 0.f};
    ak[i] = f32x4{0.f, 0.f, 0.f, 0.f};
    av[i] = f32x4{0.f, 0.f, 0.f, 0.f};
  }

#pragma unroll
  for (int ks = 0; ks < 8; ++ks) {
    bf16x8 a = *reinterpret_cast<const bf16x8*>(
        xT + swz512(w * 16 + (l & 15), ks * 64 + (l >> 4) * 16));
#pragma unroll
    for (int nf = 0; nf < 8; ++nf) {
      bf16x8 wq = *reinterpret_cast<const bf16x8*>(bq_ + (ks * 8 + nf) * 512 + l * 8);
      aq[nf] = mfma16(a, wq, aq[nf]);
      bf16x8 wk = *reinterpret_cast<const bf16x8*>(bk_ + (ks * 8 + nf) * 512 + l * 8);
      ak[nf] = mfma16(a, wk, ak[nf]);
    }
    bf16x8 wv0 = *reinterpret_cast<const bf16x8*>(bv_ + (ks * 8 + w * 2 + 0) * 512 + l * 8);
    bf16x8 wv1 = *reinterpret_cast<const bf16x8*>(bv_ + (ks * 8 + w * 2 + 1) * 512 + l * 8);
#pragma unroll
    for (int nf4 = 0; nf4 < 4; ++nf4) {
      bf16x8 bx = *reinterpret_cast<const bf16x8*>(
          xT + swz512(nf4 * 16 + (l & 15), ks * 64 + (l >> 4) * 16));
      av[nf4] = mfma16(wv0, bx, av[nf4]);
      av[4 + nf4] = mfma16(wv1, bx, av[4 + nf4]);
    }
  }

#pragma unroll
  for (int nf = 0; nf < 8; ++nf) {
    int h = nf * 16 + (l & 15);
    float biasq = bq[h], biask = bk[h];
#pragma unroll
    for (int r = 0; r < 4; ++r) {
      int n = n0 + w * 16 + (l >> 4) * 4 + r;
      // Q pre-scaled by LOG2E (k2 uses exp2 directly).
      Qo[(size_t)(b * NDIM + n) * HDIM + h] = (bf16)((aq[nf][r] + biasq) * LOG2E);
      Ko[(size_t)(b * NDIM + n) * HDIM + h] = (bf16)(ak[nf][r] + biask);
    }
  }
#pragma unroll
  for (int mf = 0; mf < 2; ++mf)
#pragma unroll
    for (int nf4 = 0; nf4 < 4; ++nf4)
#pragma unroll
      for (int r = 0; r < 4; ++r) {
        int h = w * 32 + mf * 16 + (l >> 4) * 4 + r;
        int n = n0 + nf4 * 16 + (l & 15);
        Vo[(size_t)(b * HDIM + h) * NDIM + n] = (bf16)(av[mf * 4 + nf4][r] + bv[h]);
      }
}

// ---------------------------------------------------------------------------
// Kernel 2: flash attention, 4 waves = 4 kpos-quarters, each wave carries
// TWO 32-q subtiles (q-reuse: every K/V fragment feeds 2 MFMAs; every staged
// LDS byte read exactly once). 1 wave/SIMD with 512-reg budget
// (__launch_bounds__(256,1)) -> no spills. KVB=128 (256B rows, conflict-free),
// 128KB dbuf, global_load_lds + single barrier/tile, max-free exp2 softmax
// (Q pre-scaled by log2e), in-register P, split-k-4 tree merge.
// grid 512 (XCD-pinned), 256 thr.
// ---------------------------------------------------------------------------
__global__ __launch_bounds__(256, 1) void k2_attn(
    const bf16* __restrict__ Q, const bf16* __restrict__ K,
    const bf16* __restrict__ V, bf16* __restrict__ O) {
  extern __shared__ char lds[];
  // buf0 @0, buf1 @65536; each: Kt [128 kpos][256B] @0, Vt [128 d][256B] @32768

  const int t = threadIdx.x;
  const int l = t & 63;
  const int w = t >> 6;     // 0..3 = kpos quarter
  const int hi = l >> 5;
  const int c31 = l & 31;

  const int pid = blockIdx.x;
  const int b = (pid & 7) * 2 + ((pid >> 3) >> 5);
  const int q0 = ((pid >> 3) & 31) * 64;

  // Q fragments (B-operand) for both q-subtiles.
  bf16x8 qf0[8], qf1[8];
  {
    const bf16* qb = Q + ((size_t)b * NDIM + q0 + c31) * HDIM + hi * 8;
#pragma unroll
    for (int cs = 0; cs < 8; ++cs) {
      qf0[cs] = *reinterpret_cast<const bf16x8*>(qb + cs * 16);
      qf1[cs] = *reinterpret_cast<const bf16x8*>(qb + 32 * HDIM + cs * 16);
    }
  }

  // Staging: wave w covers rows {w*4 + (l>>4)} + i*16, i=0..7, slot l&15.
  // Linear LDS dest (uniform base + lane*16); XOR swizzle folded into the
  // per-lane GLOBAL source address [rule #21].
  const int srow = w * 4 + (l >> 4);
  const int slot = l & 15;
  const int sx = srow & 15;  // i-invariant (i*16 = 0 mod 16)
  unsigned offK[8], offV[8];
#pragma unroll
  for (int i = 0; i < 8; ++i) {
    int r = srow + i * 16;
    offK[i] = (unsigned)((b * NDIM + r) * HDIM + (slot ^ sx) * 8);
    offV[i] = (unsigned)((b * HDIM + r) * NDIM + (slot ^ sx) * 8);
  }
  const int kdst = w * 1024;           // + i*4096 (+ lane*16 by HW)
  const int vdst = 32768 + w * 1024;

  f32x16 oacc0[4], oacc1[4];
#pragma unroll
  for (int dg = 0; dg < 4; ++dg)
#pragma unroll
    for (int r = 0; r < 16; ++r) { oacc0[dg][r] = 0.f; oacc1[dg][r] = 0.f; }
  float l0 = 0.f, l1 = 0.f;

  // prologue: tile 0 (16 loads per wave, 64 KB per block)
#pragma unroll
  for (int i = 0; i < 8; ++i) gload16(K + offK[i], lds + kdst + i * 4096);
#pragma unroll
  for (int i = 0; i < 8; ++i) gload16(V + offV[i], lds + vdst + i * 4096);

  const int rx = c31 & 15;

#pragma unroll 1
  for (int kt = 0; kt < NT; ++kt) {
    // Wait own tile-kt loads, then barrier: all waves' kt data present AND
    // all waves done computing kt-1 -> safe to stage kt+1 into the other buf.
    asm volatile("s_waitcnt vmcnt(0)" ::: "memory");
    __builtin_amdgcn_s_barrier();
    char* buf = lds + (kt & 1) * 65536;
    if (kt + 1 < NT) {
      char* nbuf = lds + ((kt + 1) & 1) * 65536;
#pragma unroll
      for (int i = 0; i < 8; ++i) {
        offK[i] += (unsigned)(KVB * HDIM);
        gload16(K + offK[i], nbuf + kdst + i * 4096);
      }
#pragma unroll
      for (int i = 0; i < 8; ++i) {
        offV[i] += (unsigned)KVB;
        gload16(V + offV[i], nbuf + vdst + i * 4096);
      }
    }

    const char* Kt = buf;
    const char* Vt = buf + 32768;

    // S^T = mfma(K, Q) for both q-subtiles; kf read once, used twice.
    f32x16 s0, s1;
#pragma unroll
    for (int r = 0; r < 16; ++r) { s0[r] = 0.f; s1[r] = 0.f; }
    __builtin_amdgcn_s_setprio(1);
    {
      const char* kr = Kt + (w * 32 + c31) * 256;
#pragma unroll
      for (int cs = 0; cs < 8; ++cs) {
        bf16x8 kf = *reinterpret_cast<const bf16x8*>(
            kr + (((cs * 2 + hi) ^ rx) * 16));
        s0 = mfma32(kf, qf0[cs], s0);
        s1 = mfma32(kf, qf1[cs], s1);
      }
    }
    __builtin_amdgcn_s_setprio(0);

    // Max-free softmax (Q pre-scaled: P = exp2(S')) + in-register P->bf16.
    bf16x8 pa0[2], pa1[2];
#pragma unroll
    for (int qs = 0; qs < 2; ++qs) {
      f32x16& s = qs ? s1 : s0;
      float sum = 0.f;
#pragma unroll
      for (int r = 0; r < 16; ++r) {
        float p = __builtin_amdgcn_exp2f(s[r]);
        s[r] = p;
        sum += p;
      }
      if (qs) l1 += sum; else l0 += sum;
      unsigned w0 = cvtpk(s[0], s[1]);
      unsigned w1 = cvtpk(s[2], s[3]);
      unsigned w2 = cvtpk(s[4], s[5]);
      unsigned w3 = cvtpk(s[6], s[7]);
      unsigned w4 = cvtpk(s[8], s[9]);
      unsigned w5 = cvtpk(s[10], s[11]);
      unsigned w6 = cvtpk(s[12], s[13]);
      unsigned w7 = cvtpk(s[14], s[15]);
      pswap(w0, w2); pswap(w1, w3); pswap(w4, w6); pswap(w5, w7);
      u32x4 pw0 = {w0, w1, w2, w3};
      u32x4 pw1 = {w4, w5, w6, w7};
      (qs ? pa1 : pa0)[0] = __builtin_bit_cast(bf16x8, pw0);
      (qs ? pa1 : pa0)[1] = __builtin_bit_cast(bf16x8, pw1);
    }

    // PV: vf read once, used for both q-subtiles.
    __builtin_amdgcn_s_setprio(1);
#pragma unroll
    for (int ks = 0; ks < 2; ++ks) {
#pragma unroll
      for (int dg = 0; dg < 4; ++dg) {
        const char* vr = Vt + (dg * 32 + c31) * 256;
        bf16x8 vf = *reinterpret_cast<const bf16x8*>(
            vr + (((w * 4 + ks * 2 + hi) ^ rx) * 16));
        oacc0[dg] = mfma32(pa0[ks], vf, oacc0[dg]);
        oacc1[dg] = mfma32(pa1[ks], vf, oacc1[dg]);
      }
    }
    __builtin_amdgcn_s_setprio(0);
  }

  // ---- split-k-4 merge across waves. Tile buffers dead; reuse LDS.
  l0 += __shfl_xor(l0, 32);
  l1 += __shfl_xor(l1, 32);
  float* Ls = (float*)(lds + 131072);  // [qs][w][32]
  if (l < 32) {
    Ls[(0 * 4 + w) * 32 + c31] = l0;
    Ls[(1 * 4 + w) * 32 + c31] = l1;
  }
  auto region = [&](int idx) { return (float*)(lds + idx * 32768); };
  if (w & 1) {  // waves 1,3 write
    float* R = region(w >> 1);
#pragma unroll
    for (int dg = 0; dg < 4; ++dg)
#pragma unroll
      for (int r = 0; r < 16; ++r) {
        R[((0 * 4 + dg) * 16 + r) * 64 + l] = oacc0[dg][r];
        R[((1 * 4 + dg) * 16 + r) * 64 + l] = oacc1[dg][r];
      }
  }
  __syncthreads();
  if (!(w & 1)) {  // waves 0,2 accumulate
    float* R = region(w >> 1);
#pragma unroll
    for (int dg = 0; dg < 4; ++dg)
#pragma unroll
      for (int r = 0; r < 16; ++r) {
        oacc0[dg][r] += R[((0 * 4 + dg) * 16 + r) * 64 + l];
        oacc1[dg][r] += R[((1 * 4 + dg) * 16 + r) * 64 + l];
      }
  }
  __syncthreads();
  if (w == 2) {
    float* R = region(0);
#pragma unroll
    for (int dg = 0; dg < 4; ++dg)
#pragma unroll
      for (int r = 0; r < 16; ++r) {
        R[((0 * 4 + dg) * 16 + r) * 64 + l] = oacc0[dg][r];
        R[((1 * 4 + dg) * 16 + r) * 64 + l] = oacc1[dg][r];
      }
  }
  __syncthreads();
  if (w == 0) {
    float* R = region(0);
    float linv0 = 1.0f / (Ls[c31] + Ls[32 + c31] + Ls[64 + c31] + Ls[96 + c31]);
    float linv1 = 1.0f / (Ls[128 + c31] + Ls[160 + c31] + Ls[192 + c31] + Ls[224 + c31]);
    int ib0 = __builtin_bit_cast(int, linv0);
    int ib1 = __builtin_bit_cast(int, linv1);
#pragma unroll
    for (int dg = 0; dg < 4; ++dg) {
      int h = dg * 32 + c31;
#pragma unroll
      for (int r = 0; r < 16; ++r) {
        int crow = (r & 3) + 8 * (r >> 2) + 4 * hi;
        float f0 = __builtin_bit_cast(
            float, __builtin_amdgcn_ds_bpermute(crow * 4, ib0));
        float f1 = __builtin_bit_cast(
            float, __builtin_amdgcn_ds_bpermute(crow * 4, ib1));
        float v0 = (oacc0[dg][r] + R[((0 * 4 + dg) * 16 + r) * 64 + l]) * f0;
        float v1 = (oacc1[dg][r] + R[((1 * 4 + dg) * 16 + r) * 64 + l]) * f1;
        O[((size_t)b * NDIM + q0 + crow) * HDIM + h] = (bf16)v0;
        O[((size_t)b * NDIM + q0 + 32 + crow) * HDIM + h] = (bf16)v1;
      }
    }
  }
}

// ---------------------------------------------------------------------------
// Kernel 3: out = Wf @ O + bf + x (unchanged)
// ---------------------------------------------------------------------------
__global__ __launch_bounds__(256) void k3_proj(
    const bf16* __restrict__ O, const float* __restrict__ Wf,
    const float* __restrict__ bfv, const float* __restrict__ x,
    float* __restrict__ out) {
  __shared__ char lds[49152];
  char* Wt = lds;
  char* Ot = lds + 32768;

  const int t = threadIdx.x;
  const int l = t & 63;
  const int w = t >> 6;
  const int b = blockIdx.x >> 5;
  const int n0 = (blockIdx.x & 31) * 64;

#pragma unroll
  for (int pass = 0; pass < 4; ++pass) {
    int n = pass * 16 + (t >> 4);
    int hq = t & 15;
    uint4 d = *reinterpret_cast<const uint4*>(
        O + (size_t)(b * NDIM + n0 + n) * HDIM + hq * 8);
    *reinterpret_cast<uint4*>(Ot + swz256(n, hq * 16)) = d;
  }

#pragma unroll 1
  for (int ch = 0; ch < 2; ++ch) {
    __syncthreads();
#pragma unroll
    for (int pass = 0; pass < 8; ++pass) {
      int cl = pass * 16 + (t >> 4);
      int hq = t & 15;
      const float* src = Wf + (size_t)(ch * 128 + cl) * HDIM + hq * 8;
      float4 v0 = *reinterpret_cast<const float4*>(src);
      float4 v1 = *reinterpret_cast<const float4*>(src + 4);
      *reinterpret_cast<bf16x8*>(Wt + swz256(cl, hq * 16)) = cvt8(v0, v1);
    }
    __syncthreads();

    f32x4 acc[2][4];
#pragma unroll
    for (int i = 0; i < 2; ++i)
#pragma unroll
      for (int j = 0; j < 4; ++j) acc[i][j] = f32x4{0.f, 0.f, 0.f, 0.f};

#pragma unroll
    for (int ks = 0; ks < 4; ++ks) {
      int cb = ks * 64 + (l >> 4) * 16;
      bf16x8 a0 = *reinterpret_cast<const bf16x8*>(
          Wt + swz256(w * 32 + (l & 15), cb));
      bf16x8 a1 = *reinterpret_cast<const bf16x8*>(
          Wt + swz256(w * 32 + 16 + (l & 15), cb));
#pragma unroll
      for (int nf = 0; nf < 4; ++nf) {
        bf16x8 bb = *reinterpret_cast<const bf16x8*>(
            Ot + swz256(nf * 16 + (l & 15), cb));
        acc[0][nf] = mfma16(a0, bb, acc[0][nf]);
        acc[1][nf] = mfma16(a1, bb, acc[1][nf]);
      }
    }

#pragma unroll
    for (int mf = 0; mf < 2; ++mf)
#pragma unroll
      for (int nf = 0; nf < 4; ++nf)
#pragma unroll
        for (int r = 0; r < 4; ++r) {
          int c = ch * 128 + w * 32 + mf * 16 + (l >> 4) * 4 + r;
          int n = n0 + nf * 16 + (l & 15);
          size_t idx = (size_t)(b * CDIM + c) * NDIM + n;
          out[idx] = acc[mf][nf][r] + bfv[c] + x[idx];
        }
  }
}

extern "C" void kernel_launch(void* const* d_in, const int* in_sizes, int n_in,
                              void* d_out, int out_size, void* d_ws,
                              size_t ws_size, hipStream_t stream) {
  (void)in_sizes; (void)n_in;
  const float* x = (const float*)d_in[0];
  const float* Wq = (const float*)d_in[1];
  const float* bq = (const float*)d_in[2];
  const float* Wk = (const float*)d_in[3];
  const float* bk = (const float*)d_in[4];
  const float* Wv = (const float*)d_in[5];
  const float* bv = (const float*)d_in[6];
  const float* Wf = (const float*)d_in[7];
  const float* bfv = (const float*)d_in[8];
  float* out = (float*)d_out;

  if (ws_size < (24u << 20)) return;
  char* ws = (char*)d_ws;
  bf16* Qb = (bf16*)(ws);                  // 8 MB [B][N][H]; reused as O
  bf16* Kb = (bf16*)(ws + (8u << 20));     // 8 MB [B][N][H]
  bf16* Vb = (bf16*)(ws + (16u << 20));    // 8 MB [B][H][N]

  // Blocked-bf16 W lives in d_out's tail (k3 overwrites it afterwards).
  const size_t out_bytes = (size_t)out_size * 4;
  bf16* Wblk = (bf16*)((char*)d_out + out_bytes - 196608);

  const unsigned k2_lds = 132096;  // 2x64KB dbuf + 1KB Ls (merge reuses dbuf)
  hipFuncSetAttribute(reinterpret_cast<const void*>(k2_attn),
                      hipFuncAttributeMaxDynamicSharedMemorySize, (int)k2_lds);

  k0_prep<<<48, 256, 0, stream>>>(Wq, Wk, Wv, Wblk);
  k1_qkv<<<512, 256, 0, stream>>>(x, Wblk, bq, bk, bv, Qb, Kb, Vb);
  k2_attn<<<512, 256, k2_lds, stream>>>(Qb, Kb, Vb, Qb);
  k3_proj<<<512, 256, 0, stream>>>(Qb, Wf, bfv, x, out);
}

// Round 9
// 110.873 us; speedup vs baseline: 1.2039x; 1.2039x over previous
//
#include <hip/hip_runtime.h>
#include <hip/hip_bf16.h>

#define BATCH 16
#define CDIM 256
#define NDIM 2048
#define HDIM 128
#define KVB 64
#define NT (NDIM / KVB)

typedef __bf16 bf16;
typedef float f32x4 __attribute__((ext_vector_type(4)));
typedef float f32x16 __attribute__((ext_vector_type(16)));
typedef bf16 bf16x8 __attribute__((ext_vector_type(8)));
typedef unsigned int u32x4 __attribute__((ext_vector_type(4)));
typedef unsigned int u32x2 __attribute__((ext_vector_type(2)));

#define LOG2E 1.4426950408889634f

__device__ __forceinline__ int swz512(int row, int colbyte) {
  return row * 512 + (colbyte ^ ((row & 15) << 4));
}
__device__ __forceinline__ int swz256(int row, int colbyte) {
  return row * 256 + (colbyte ^ ((row & 7) << 4));
}

__device__ __forceinline__ f32x4 mfma16(bf16x8 a, bf16x8 b, f32x4 c) {
  return __builtin_amdgcn_mfma_f32_16x16x32_bf16(a, b, c, 0, 0, 0);
}
__device__ __forceinline__ f32x16 mfma32(bf16x8 a, bf16x8 b, f32x16 c) {
  return __builtin_amdgcn_mfma_f32_32x32x16_bf16(a, b, c, 0, 0, 0);
}

__device__ __forceinline__ unsigned cvtpk(float lo, float hi) {
  unsigned r;
  asm("v_cvt_pk_bf16_f32 %0, %1, %2" : "=v"(r) : "v"(lo), "v"(hi));
  return r;
}
__device__ __forceinline__ void pswap(unsigned &a, unsigned &b) {
  asm volatile("v_permlane32_swap_b32 %0, %1" : "+v"(a), "+v"(b));
}

__device__ __forceinline__ void gload16(const bf16* g, char* l) {
  __builtin_amdgcn_global_load_lds(
      (const __attribute__((address_space(1))) void*)g,
      (__attribute__((address_space(3))) void*)l, 16, 0, 0);
}

__device__ __forceinline__ bf16x8 cvt8(float4 a, float4 b) {
  bf16x8 o;
  o[0] = (bf16)a.x; o[1] = (bf16)a.y; o[2] = (bf16)a.z; o[3] = (bf16)a.w;
  o[4] = (bf16)b.x; o[5] = (bf16)b.y; o[6] = (bf16)b.z; o[7] = (bf16)b.w;
  return o;
}

// ---------------------------------------------------------------------------
// Kernel 0: pack Wq/Wk/Wv into bf16 MFMA-fragment-blocked layout.
// ---------------------------------------------------------------------------
__global__ __launch_bounds__(256) void k0_prep(
    const float* __restrict__ Wq, const float* __restrict__ Wk,
    const float* __restrict__ Wv, bf16* __restrict__ blk) {
  int tg = blockIdx.x * 256 + threadIdx.x;
  int f = tg >> 6, l = tg & 63;
  const float* W = (f < 64) ? Wq : (f < 128 ? Wk : Wv);
  int ks = (f >> 3) & 7, hb = f & 7;
  const float* src = W + (size_t)(hb * 16 + (l & 15)) * CDIM + ks * 32 + (l >> 4) * 8;
  float4 v0 = *reinterpret_cast<const float4*>(src);
  float4 v1 = *reinterpret_cast<const float4*>(src + 4);
  *reinterpret_cast<bf16x8*>(blk + f * 512 + l * 8) = cvt8(v0, v1);
}

// ---------------------------------------------------------------------------
// Kernel 1: fused QKV projection (W direct from L2, shfl-transpose staging,
// one barrier). Q output pre-scaled by LOG2E for k2's exp2-direct softmax.
// ---------------------------------------------------------------------------
__global__ __launch_bounds__(256, 3) void k1_qkv(
    const float* __restrict__ x, const bf16* __restrict__ blk,
    const float* __restrict__ bq, const float* __restrict__ bk,
    const float* __restrict__ bv,
    bf16* __restrict__ Qo, bf16* __restrict__ Ko, bf16* __restrict__ Vo) {
  __shared__ char xT[32768];  // [64 n][256 c] bf16, 512B rows, swz512

  const int t = threadIdx.x;
  const int l = t & 63;
  const int w = t >> 6;
  const int q = (l >> 4) & 3;
  const int b = blockIdx.x >> 5;
  const int n0 = (blockIdx.x & 31) * 64;

#pragma unroll
  for (int p = 0; p < 16; ++p) {
    int c = w * 64 + p * 4 + q;
    float4 v = *reinterpret_cast<const float4*>(
        x + (size_t)(b * CDIM + c) * NDIM + n0 + (l & 15) * 4);
    float t0 = __shfl_xor(v.x, 16), t1 = __shfl_xor(v.y, 16);
    float t2 = __shfl_xor(v.z, 16), t3 = __shfl_xor(v.w, 16);
    float4 wv;
    if ((q & 1) == 0) wv = make_float4(v.x, t0, v.z, t2);
    else              wv = make_float4(t1, v.y, t3, v.w);
    float s0 = __shfl_xor(wv.x, 32), s1 = __shfl_xor(wv.y, 32);
    float s2 = __shfl_xor(wv.z, 32), s3 = __shfl_xor(wv.w, 32);
    float4 z;
    if ((q & 2) == 0) z = make_float4(wv.x, wv.y, s0, s1);
    else              z = make_float4(s2, s3, wv.z, wv.w);
    u32x2 pk = {cvtpk(z.x, z.y), cvtpk(z.z, z.w)};
    int n = (l & 15) * 4 + q;
    int slot = w * 8 + (p >> 1);
    *reinterpret_cast<u32x2*>(
        xT + n * 512 + ((slot ^ (n & 15)) * 16 + (p & 1) * 8)) = pk;
  }
  __syncthreads();

  const bf16* bq_ = blk;
  const bf16* bk_ = blk + 64 * 512;
  const bf16* bv_ = blk + 128 * 512;

  f32x4 aq[8], ak[8], av[8];
#pragma unroll
  for (int i = 0; i < 8; ++i) {
    aq[i] = f32x4{0.f, 0.f, 0.f, 0.f};
    ak[i] = f32x4{0.f, 0.f, 0.f, 0.f};
    av[i] = f32x4{0.f, 0.f, 0.f, 0.f};
  }

#pragma unroll
  for (int ks = 0; ks < 8; ++ks) {
    bf16x8 a = *reinterpret_cast<const bf16x8*>(
        xT + swz512(w * 16 + (l & 15), ks * 64 + (l >> 4) * 16));
#pragma unroll
    for (int nf = 0; nf < 8; ++nf) {
      bf16x8 wq = *reinterpret_cast<const bf16x8*>(bq_ + (ks * 8 + nf) * 512 + l * 8);
      aq[nf] = mfma16(a, wq, aq[nf]);
      bf16x8 wk = *reinterpret_cast<const bf16x8*>(bk_ + (ks * 8 + nf) * 512 + l * 8);
      ak[nf] = mfma16(a, wk, ak[nf]);
    }
    bf16x8 wv0 = *reinterpret_cast<const bf16x8*>(bv_ + (ks * 8 + w * 2 + 0) * 512 + l * 8);
    bf16x8 wv1 = *reinterpret_cast<const bf16x8*>(bv_ + (ks * 8 + w * 2 + 1) * 512 + l * 8);
#pragma unroll
    for (int nf4 = 0; nf4 < 4; ++nf4) {
      bf16x8 bx = *reinterpret_cast<const bf16x8*>(
          xT + swz512(nf4 * 16 + (l & 15), ks * 64 + (l >> 4) * 16));
      av[nf4] = mfma16(wv0, bx, av[nf4]);
      av[4 + nf4] = mfma16(wv1, bx, av[4 + nf4]);
    }
  }

#pragma unroll
  for (int nf = 0; nf < 8; ++nf) {
    int h = nf * 16 + (l & 15);
    float biasq = bq[h], biask = bk[h];
#pragma unroll
    for (int r = 0; r < 4; ++r) {
      int n = n0 + w * 16 + (l >> 4) * 4 + r;
      // Q pre-scaled by LOG2E (k2 uses exp2 directly).
      Qo[(size_t)(b * NDIM + n) * HDIM + h] = (bf16)((aq[nf][r] + biasq) * LOG2E);
      Ko[(size_t)(b * NDIM + n) * HDIM + h] = (bf16)(ak[nf][r] + biask);
    }
  }
#pragma unroll
  for (int mf = 0; mf < 2; ++mf)
#pragma unroll
    for (int nf4 = 0; nf4 < 4; ++nf4)
#pragma unroll
      for (int r = 0; r < 4; ++r) {
        int h = w * 32 + mf * 16 + (l >> 4) * 4 + r;
        int n = n0 + nf4 * 16 + (l & 15);
        Vo[(size_t)(b * HDIM + h) * NDIM + n] = (bf16)(av[mf * 4 + nf4][r] + bv[h]);
      }
}

// ---------------------------------------------------------------------------
// Kernel 2: flash attention (R5 structure — fastest measured): max-free
// exp2-direct softmax (Q pre-scaled), KVB=64 double-buffered (64 KB LDS ->
// 2 independent blocks/CU), global_load_lds with counted vmcnt(8),
// in-register P, split-k-2 merge. grid 512 (XCD-swizzled), 256 thr = 4 waves
// = 2 q-subtiles(32) x 2 kpos-halves(32).
// ---------------------------------------------------------------------------
__global__ __launch_bounds__(256, 2) void k2_attn(
    const bf16* __restrict__ Q, const bf16* __restrict__ K,
    const bf16* __restrict__ V, bf16* __restrict__ O) {
  extern __shared__ char lds[];
  // buf0 @0, buf1 @32768; each: Kt [64 kpos][256B] @0, Vt [128 d][128B] @16384

  const int t = threadIdx.x;
  const int l = t & 63;
  const int w = t >> 6;     // 0..3
  const int wm = w & 1;     // q-subtile (32 rows)
  const int wk = w >> 1;    // kpos half (32 kpos)
  const int hi = l >> 5;
  const int c31 = l & 31;

  const int pid = blockIdx.x;
  const int b = (pid & 7) * 2 + ((pid >> 3) >> 5);
  const int q0 = ((pid >> 3) & 31) * 64;

  // Q fragments (B-operand): lane c31 = q-row, elem j at chunk cs -> d.
  bf16x8 qf[8];
  {
    const bf16* qb = Q + ((size_t)b * NDIM + q0 + wm * 32 + c31) * HDIM + hi * 8;
#pragma unroll
    for (int cs = 0; cs < 8; ++cs)
      qf[cs] = *reinterpret_cast<const bf16x8*>(qb + cs * 16);
  }

  // Staging (all 4 waves stage both K and V slices). Linear LDS dest
  // (wave-uniform base + lane*16); XOR swizzle folded into global source.
  unsigned offK[4], offV[4];
  {
    const int krow = w * 16 + (l >> 4);
    const int kslot = l & 15;
#pragma unroll
    for (int i = 0; i < 4; ++i) {
      int r = krow + i * 4;
      offK[i] = (unsigned)((b * NDIM + r) * HDIM + (kslot ^ (r & 15)) * 8);
    }
    const int vrow = w * 32 + (l >> 3);
    const int vslot = l & 7;
#pragma unroll
    for (int i = 0; i < 4; ++i) {
      int r = vrow + i * 8;
      offV[i] = (unsigned)((b * HDIM + r) * NDIM + (vslot ^ (r & 7)) * 8);
    }
  }
  const int kbase = w * 4096;           // + i*1024 (+ lane*16 by HW)
  const int vbase = 16384 + w * 4096;

  f32x16 oacc[4];
#pragma unroll
  for (int dg = 0; dg < 4; ++dg)
#pragma unroll
    for (int r = 0; r < 16; ++r) oacc[dg][r] = 0.f;
  float l_run = 0.f;

  // prologue: tile 0
#pragma unroll
  for (int i = 0; i < 4; ++i) gload16(K + offK[i], lds + kbase + i * 1024);
#pragma unroll
  for (int i = 0; i < 4; ++i) gload16(V + offV[i], lds + vbase + i * 1024);

  const int krow = wk * 32 + c31;
  const int rxk = krow & 15;
  const int rxv = c31 & 7;

#pragma unroll 1
  for (int kt = 0; kt < NT; ++kt) {
    char* buf = lds + (kt & 1) * 32768;
    if (kt + 1 < NT) {
      char* nbuf = lds + ((kt + 1) & 1) * 32768;
#pragma unroll
      for (int i = 0; i < 4; ++i) {
        offK[i] += (unsigned)(KVB * HDIM);
        gload16(K + offK[i], nbuf + kbase + i * 1024);
      }
#pragma unroll
      for (int i = 0; i < 4; ++i) {
        offV[i] += (unsigned)KVB;
        gload16(V + offV[i], nbuf + vbase + i * 1024);
      }
      asm volatile("s_waitcnt vmcnt(8)" ::: "memory");  // tile kt landed
    } else {
      asm volatile("s_waitcnt vmcnt(0)" ::: "memory");
    }
    __builtin_amdgcn_s_barrier();

    const char* Kt = buf;
    const char* Vt = buf + 16384;

    // S^T = mfma(K, Q): D[kpos][q], lane = q, regs = kpos (wave's 32 kpos).
    f32x16 s;
#pragma unroll
    for (int r = 0; r < 16; ++r) s[r] = 0.f;
    __builtin_amdgcn_s_setprio(1);
    {
      const char* kr = Kt + krow * 256;
#pragma unroll
      for (int cs = 0; cs < 8; ++cs) {
        bf16x8 kf = *reinterpret_cast<const bf16x8*>(
            kr + (((cs * 2 + hi) ^ rxk) * 16));
        s = mfma32(kf, qf[cs], s);
      }
    }
    __builtin_amdgcn_s_setprio(0);

    // Max-free softmax: P = exp2(S') unnormalized (Q pre-scaled by log2e).
    float sum = 0.f;
#pragma unroll
    for (int r = 0; r < 16; ++r) {
      float p = __builtin_amdgcn_exp2f(s[r]);
      s[r] = p;
      sum += p;
    }
    l_run += sum;

    // P -> bf16 A-fragments in-register.
    unsigned w0 = cvtpk(s[0], s[1]);
    unsigned w1 = cvtpk(s[2], s[3]);
    unsigned w2 = cvtpk(s[4], s[5]);
    unsigned w3 = cvtpk(s[6], s[7]);
    unsigned w4 = cvtpk(s[8], s[9]);
    unsigned w5 = cvtpk(s[10], s[11]);
    unsigned w6 = cvtpk(s[12], s[13]);
    unsigned w7 = cvtpk(s[14], s[15]);
    pswap(w0, w2); pswap(w1, w3); pswap(w4, w6); pswap(w5, w7);
    u32x4 pw0 = {w0, w1, w2, w3};
    u32x4 pw1 = {w4, w5, w6, w7};
    bf16x8 pa0 = __builtin_bit_cast(bf16x8, pw0);
    bf16x8 pa1 = __builtin_bit_cast(bf16x8, pw1);

    // PV: O[q][h] += P[q][kpos] V[kpos][h].
    __builtin_amdgcn_s_setprio(1);
#pragma unroll
    for (int dg = 0; dg < 4; ++dg) {
      const char* vr = Vt + (dg * 32 + c31) * 128;
      bf16x8 vf0 = *reinterpret_cast<const bf16x8*>(
          vr + (((wk * 4 + 0 + hi) ^ rxv) * 16));
      oacc[dg] = mfma32(pa0, vf0, oacc[dg]);
      bf16x8 vf1 = *reinterpret_cast<const bf16x8*>(
          vr + (((wk * 4 + 2 + hi) ^ rxv) * 16));
      oacc[dg] = mfma32(pa1, vf1, oacc[dg]);
    }
    __builtin_amdgcn_s_setprio(0);
    __builtin_amdgcn_s_barrier();  // all waves done reading buf
  }

  // ---- split-k-2 merge (wk pairs). Tile buffers dead; reuse LDS.
  l_run += __shfl_xor(l_run, 32);
  float* O1 = (float*)lds;             // [wm][dg][r][64 lanes] 2 x 16 KB
  float* L1 = (float*)(lds + 32768);   // [2][32]
  if (wk == 1) {
#pragma unroll
    for (int dg = 0; dg < 4; ++dg)
#pragma unroll
      for (int r = 0; r < 16; ++r)
        O1[wm * 4096 + (dg * 16 + r) * 64 + l] = oacc[dg][r];
    if (l < 32) L1[wm * 32 + c31] = l_run;
  }
  __syncthreads();
  if (wk == 0) {
    float linv = 1.0f / (l_run + L1[wm * 32 + c31]);
    int ibits = __builtin_bit_cast(int, linv);
#pragma unroll
    for (int dg = 0; dg < 4; ++dg) {
      int h = dg * 32 + c31;
#pragma unroll
      for (int r = 0; r < 16; ++r) {
        int crow = (r & 3) + 8 * (r >> 2) + 4 * hi;
        float fr = __builtin_bit_cast(
            float, __builtin_amdgcn_ds_bpermute(crow * 4, ibits));
        float val = (oacc[dg][r] + O1[wm * 4096 + (dg * 16 + r) * 64 + l]) * fr;
        int n = q0 + wm * 32 + crow;
        O[((size_t)b * NDIM + n) * HDIM + h] = (bf16)val;
      }
    }
  }
}

// ---------------------------------------------------------------------------
// Kernel 3: out = Wf @ O + bf + x (unchanged; near HBM roofline)
// ---------------------------------------------------------------------------
__global__ __launch_bounds__(256) void k3_proj(
    const bf16* __restrict__ O, const float* __restrict__ Wf,
    const float* __restrict__ bfv, const float* __restrict__ x,
    float* __restrict__ out) {
  __shared__ char lds[49152];
  char* Wt = lds;
  char* Ot = lds + 32768;

  const int t = threadIdx.x;
  const int l = t & 63;
  const int w = t >> 6;
  const int b = blockIdx.x >> 5;
  const int n0 = (blockIdx.x & 31) * 64;

#pragma unroll
  for (int pass = 0; pass < 4; ++pass) {
    int n = pass * 16 + (t >> 4);
    int hq = t & 15;
    uint4 d = *reinterpret_cast<const uint4*>(
        O + (size_t)(b * NDIM + n0 + n) * HDIM + hq * 8);
    *reinterpret_cast<uint4*>(Ot + swz256(n, hq * 16)) = d;
  }

#pragma unroll 1
  for (int ch = 0; ch < 2; ++ch) {
    __syncthreads();
#pragma unroll
    for (int pass = 0; pass < 8; ++pass) {
      int cl = pass * 16 + (t >> 4);
      int hq = t & 15;
      const float* src = Wf + (size_t)(ch * 128 + cl) * HDIM + hq * 8;
      float4 v0 = *reinterpret_cast<const float4*>(src);
      float4 v1 = *reinterpret_cast<const float4*>(src + 4);
      *reinterpret_cast<bf16x8*>(Wt + swz256(cl, hq * 16)) = cvt8(v0, v1);
    }
    __syncthreads();

    f32x4 acc[2][4];
#pragma unroll
    for (int i = 0; i < 2; ++i)
#pragma unroll
      for (int j = 0; j < 4; ++j) acc[i][j] = f32x4{0.f, 0.f, 0.f, 0.f};

#pragma unroll
    for (int ks = 0; ks < 4; ++ks) {
      int cb = ks * 64 + (l >> 4) * 16;
      bf16x8 a0 = *reinterpret_cast<const bf16x8*>(
          Wt + swz256(w * 32 + (l & 15), cb));
      bf16x8 a1 = *reinterpret_cast<const bf16x8*>(
          Wt + swz256(w * 32 + 16 + (l & 15), cb));
#pragma unroll
      for (int nf = 0; nf < 4; ++nf) {
        bf16x8 bb = *reinterpret_cast<const bf16x8*>(
            Ot + swz256(nf * 16 + (l & 15), cb));
        acc[0][nf] = mfma16(a0, bb, acc[0][nf]);
        acc[1][nf] = mfma16(a1, bb, acc[1][nf]);
      }
    }

#pragma unroll
    for (int mf = 0; mf < 2; ++mf)
#pragma unroll
      for (int nf = 0; nf < 4; ++nf)
#pragma unroll
        for (int r = 0; r < 4; ++r) {
          int c = ch * 128 + w * 32 + mf * 16 + (l >> 4) * 4 + r;
          int n = n0 + nf * 16 + (l & 15);
          size_t idx = (size_t)(b * CDIM + c) * NDIM + n;
          out[idx] = acc[mf][nf][r] + bfv[c] + x[idx];
        }
  }
}

extern "C" void kernel_launch(void* const* d_in, const int* in_sizes, int n_in,
                              void* d_out, int out_size, void* d_ws,
                              size_t ws_size, hipStream_t stream) {
  (void)in_sizes; (void)n_in;
  const float* x = (const float*)d_in[0];
  const float* Wq = (const float*)d_in[1];
  const float* bq = (const float*)d_in[2];
  const float* Wk = (const float*)d_in[3];
  const float* bk = (const float*)d_in[4];
  const float* Wv = (const float*)d_in[5];
  const float* bv = (const float*)d_in[6];
  const float* Wf = (const float*)d_in[7];
  const float* bfv = (const float*)d_in[8];
  float* out = (float*)d_out;

  if (ws_size < (24u << 20)) return;
  char* ws = (char*)d_ws;
  bf16* Qb = (bf16*)(ws);                  // 8 MB [B][N][H]; reused as O
  bf16* Kb = (bf16*)(ws + (8u << 20));     // 8 MB [B][N][H]
  bf16* Vb = (bf16*)(ws + (16u << 20));    // 8 MB [B][H][N]

  // Blocked-bf16 W lives in d_out's tail (k3 overwrites it afterwards).
  const size_t out_bytes = (size_t)out_size * 4;
  bf16* Wblk = (bf16*)((char*)d_out + out_bytes - 196608);

  const unsigned k2_lds = 65536;  // 2 x 32 KB double buffer (merge reuses it)
  hipFuncSetAttribute(reinterpret_cast<const void*>(k2_attn),
                      hipFuncAttributeMaxDynamicSharedMemorySize, (int)k2_lds);

  k0_prep<<<48, 256, 0, stream>>>(Wq, Wk, Wv, Wblk);
  k1_qkv<<<512, 256, 0, stream>>>(x, Wblk, bq, bk, bv, Qb, Kb, Vb);
  k2_attn<<<512, 256, k2_lds, stream>>>(Qb, Kb, Vb, Qb);
  k3_proj<<<512, 256, 0, stream>>>(Qb, Wf, bfv, x, out);
}

// Round 10
// 98.714 us; speedup vs baseline: 1.3522x; 1.1232x over previous
//
#include <hip/hip_runtime.h>
#include <hip/hip_bf16.h>

#define BATCH 16
#define CDIM 256
#define NDIM 2048
#define HDIM 128
#define KVB 64
#define NT (NDIM / KVB)

typedef __bf16 bf16;
typedef float f32x4 __attribute__((ext_vector_type(4)));
typedef float f32x16 __attribute__((ext_vector_type(16)));
typedef bf16 bf16x8 __attribute__((ext_vector_type(8)));
typedef unsigned int u32x4 __attribute__((ext_vector_type(4)));
typedef unsigned int u32x2 __attribute__((ext_vector_type(2)));

#define LOG2E 1.4426950408889634f

__device__ __forceinline__ int swz512(int row, int colbyte) {
  return row * 512 + (colbyte ^ ((row & 15) << 4));
}
__device__ __forceinline__ int swz256(int row, int colbyte) {
  return row * 256 + (colbyte ^ ((row & 7) << 4));
}

__device__ __forceinline__ f32x4 mfma16(bf16x8 a, bf16x8 b, f32x4 c) {
  return __builtin_amdgcn_mfma_f32_16x16x32_bf16(a, b, c, 0, 0, 0);
}
__device__ __forceinline__ f32x16 mfma32(bf16x8 a, bf16x8 b, f32x16 c) {
  return __builtin_amdgcn_mfma_f32_32x32x16_bf16(a, b, c, 0, 0, 0);
}

__device__ __forceinline__ unsigned cvtpk(float lo, float hi) {
  unsigned r;
  asm("v_cvt_pk_bf16_f32 %0, %1, %2" : "=v"(r) : "v"(lo), "v"(hi));
  return r;
}
__device__ __forceinline__ void pswap(unsigned &a, unsigned &b) {
  asm volatile("v_permlane32_swap_b32 %0, %1" : "+v"(a), "+v"(b));
}

__device__ __forceinline__ void gload16(const bf16* g, char* l) {
  __builtin_amdgcn_global_load_lds(
      (const __attribute__((address_space(1))) void*)g,
      (__attribute__((address_space(3))) void*)l, 16, 0, 0);
}

__device__ __forceinline__ bf16x8 cvt8(float4 a, float4 b) {
  bf16x8 o;
  o[0] = (bf16)a.x; o[1] = (bf16)a.y; o[2] = (bf16)a.z; o[3] = (bf16)a.w;
  o[4] = (bf16)b.x; o[5] = (bf16)b.y; o[6] = (bf16)b.z; o[7] = (bf16)b.w;
  return o;
}

// ---------------------------------------------------------------------------
// Kernel 1: fused QKV projection. R5's proven LDS-staged-W structure, with
// the verified shfl-transpose xT staging (conflict-light) spliced in, and
// Q output pre-scaled by LOG2E for k2's exp2-direct softmax.
// grid 512 = (b:16) x (ntile:32, 64 cols), 256 thr = 4 waves.
// ---------------------------------------------------------------------------
__global__ __launch_bounds__(256) void k1_qkv(
    const float* __restrict__ x,
    const float* __restrict__ Wq, const float* __restrict__ bq,
    const float* __restrict__ Wk, const float* __restrict__ bk,
    const float* __restrict__ Wv, const float* __restrict__ bv,
    bf16* __restrict__ Qo, bf16* __restrict__ Ko, bf16* __restrict__ Vo) {
  __shared__ char lds[65536];
  char* xT = lds;            // [64 n][256 c] bf16, 512B rows, swz512 (32 KB)
  char* Wt = lds + 32768;    // [128 h][128 c-half] bf16, swz256 (32 KB)

  const int t = threadIdx.x;
  const int l = t & 63;
  const int w = t >> 6;
  const int q = (l >> 4) & 3;
  const int b = blockIdx.x >> 5;
  const int n0 = (blockIdx.x & 31) * 64;

  // Stage xT via in-register 4x4 shfl transpose (verified swz512-compatible).
#pragma unroll
  for (int p = 0; p < 16; ++p) {
    int c = w * 64 + p * 4 + q;
    float4 v = *reinterpret_cast<const float4*>(
        x + (size_t)(b * CDIM + c) * NDIM + n0 + (l & 15) * 4);
    float t0 = __shfl_xor(v.x, 16), t1 = __shfl_xor(v.y, 16);
    float t2 = __shfl_xor(v.z, 16), t3 = __shfl_xor(v.w, 16);
    float4 wv;
    if ((q & 1) == 0) wv = make_float4(v.x, t0, v.z, t2);
    else              wv = make_float4(t1, v.y, t3, v.w);
    float s0 = __shfl_xor(wv.x, 32), s1 = __shfl_xor(wv.y, 32);
    float s2 = __shfl_xor(wv.z, 32), s3 = __shfl_xor(wv.w, 32);
    float4 z;
    if ((q & 2) == 0) z = make_float4(wv.x, wv.y, s0, s1);
    else              z = make_float4(s2, s3, wv.z, wv.w);
    u32x2 pk = {cvtpk(z.x, z.y), cvtpk(z.z, z.w)};
    int n = (l & 15) * 4 + q;
    int slot = w * 8 + (p >> 1);
    *reinterpret_cast<u32x2*>(
        xT + n * 512 + ((slot ^ (n & 15)) * 16 + (p & 1) * 8)) = pk;
  }

  const float* Wp[3] = {Wq, Wk, Wv};
  const float* bp[3] = {bq, bk, bv};

#pragma unroll 1
  for (int p = 0; p < 3; ++p) {
    f32x4 acc[8];
#pragma unroll
    for (int i = 0; i < 8; ++i) acc[i] = f32x4{0.f, 0.f, 0.f, 0.f};

#pragma unroll 1
    for (int kh = 0; kh < 2; ++kh) {
      __syncthreads();  // prev compute done reading Wt (covers xT stage too)
#pragma unroll
      for (int pass = 0; pass < 8; ++pass) {
        int h = pass * 16 + (t >> 4);
        int cq = t & 15;
        const float* src = Wp[p] + (size_t)h * CDIM + kh * 128 + cq * 8;
        float4 v0 = *reinterpret_cast<const float4*>(src);
        float4 v1 = *reinterpret_cast<const float4*>(src + 4);
        *reinterpret_cast<bf16x8*>(Wt + swz256(h, cq * 16)) = cvt8(v0, v1);
      }
      __syncthreads();

      if (p < 2) {
#pragma unroll
        for (int ks = 0; ks < 4; ++ks) {
          int cb2 = ks * 64 + (l >> 4) * 16;
          bf16x8 a = *reinterpret_cast<const bf16x8*>(
              xT + swz512(w * 16 + (l & 15), kh * 256 + cb2));
#pragma unroll
          for (int nf = 0; nf < 8; ++nf) {
            bf16x8 bb = *reinterpret_cast<const bf16x8*>(
                Wt + swz256(nf * 16 + (l & 15), cb2));
            acc[nf] = mfma16(a, bb, acc[nf]);
          }
        }
      } else {
#pragma unroll
        for (int ks = 0; ks < 4; ++ks) {
          int cb2 = ks * 64 + (l >> 4) * 16;
          bf16x8 a0 = *reinterpret_cast<const bf16x8*>(
              Wt + swz256(w * 32 + (l & 15), cb2));
          bf16x8 a1 = *reinterpret_cast<const bf16x8*>(
              Wt + swz256(w * 32 + 16 + (l & 15), cb2));
#pragma unroll
          for (int nf = 0; nf < 4; ++nf) {
            bf16x8 bb = *reinterpret_cast<const bf16x8*>(
                xT + swz512(nf * 16 + (l & 15), kh * 256 + cb2));
            acc[nf] = mfma16(a0, bb, acc[nf]);
            acc[4 + nf] = mfma16(a1, bb, acc[4 + nf]);
          }
        }
      }
    }

    if (p < 2) {
      bf16* dst = (p == 0) ? Qo : Ko;
      const float scale = (p == 0) ? LOG2E : 1.0f;  // Q pre-scaled for exp2
#pragma unroll
      for (int nf = 0; nf < 8; ++nf) {
        float bias = bp[p][nf * 16 + (l & 15)];
#pragma unroll
        for (int r = 0; r < 4; ++r) {
          int n = n0 + w * 16 + (l >> 4) * 4 + r;
          int h = nf * 16 + (l & 15);
          dst[(size_t)(b * NDIM + n) * HDIM + h] = (bf16)((acc[nf][r] + bias) * scale);
        }
      }
    } else {
#pragma unroll
      for (int mf = 0; mf < 2; ++mf)
#pragma unroll
        for (int nf = 0; nf < 4; ++nf)
#pragma unroll
          for (int r = 0; r < 4; ++r) {
            int h = w * 32 + mf * 16 + (l >> 4) * 4 + r;
            int n = n0 + nf * 16 + (l & 15);
            Vo[(size_t)(b * HDIM + h) * NDIM + n] =
                (bf16)(acc[mf * 4 + nf][r] + bp[2][h]);
          }
    }
  }
}

// ---------------------------------------------------------------------------
// Kernel 2: flash attention (R5 proven structure) + exp2-direct softmax
// (Q pre-scaled) + V-fragment prefetch BEFORE softmax (LDS latency hides
// under the exp2/pack VALU chain) + tree-sum.
// grid 512 (XCD-swizzled), 256 thr = 4 waves = 2 q-subtiles x 2 kpos-halves;
// KVB=64 dbuf (64 KB -> 2 independent blocks/CU), counted vmcnt(8).
// ---------------------------------------------------------------------------
__global__ __launch_bounds__(256, 2) void k2_attn(
    const bf16* __restrict__ Q, const bf16* __restrict__ K,
    const bf16* __restrict__ V, bf16* __restrict__ O) {
  extern __shared__ char lds[];
  // buf0 @0, buf1 @32768; each: Kt [64 kpos][256B] @0, Vt [128 d][128B] @16384

  const int t = threadIdx.x;
  const int l = t & 63;
  const int w = t >> 6;     // 0..3
  const int wm = w & 1;     // q-subtile (32 rows)
  const int wk = w >> 1;    // kpos half (32 kpos)
  const int hi = l >> 5;
  const int c31 = l & 31;

  const int pid = blockIdx.x;
  const int b = (pid & 7) * 2 + ((pid >> 3) >> 5);
  const int q0 = ((pid >> 3) & 31) * 64;

  // Q fragments (B-operand): lane c31 = q-row, elem j at chunk cs -> d.
  bf16x8 qf[8];
  {
    const bf16* qb = Q + ((size_t)b * NDIM + q0 + wm * 32 + c31) * HDIM + hi * 8;
#pragma unroll
    for (int cs = 0; cs < 8; ++cs)
      qf[cs] = *reinterpret_cast<const bf16x8*>(qb + cs * 16);
  }

  // Staging (all 4 waves stage both K and V slices). Linear LDS dest
  // (wave-uniform base + lane*16); XOR swizzle folded into global source.
  unsigned offK[4], offV[4];
  {
    const int krow = w * 16 + (l >> 4);
    const int kslot = l & 15;
#pragma unroll
    for (int i = 0; i < 4; ++i) {
      int r = krow + i * 4;
      offK[i] = (unsigned)((b * NDIM + r) * HDIM + (kslot ^ (r & 15)) * 8);
    }
    const int vrow = w * 32 + (l >> 3);
    const int vslot = l & 7;
#pragma unroll
    for (int i = 0; i < 4; ++i) {
      int r = vrow + i * 8;
      offV[i] = (unsigned)((b * HDIM + r) * NDIM + (vslot ^ (r & 7)) * 8);
    }
  }
  const int kbase = w * 4096;           // + i*1024 (+ lane*16 by HW)
  const int vbase = 16384 + w * 4096;

  f32x16 oacc[4];
#pragma unroll
  for (int dg = 0; dg < 4; ++dg)
#pragma unroll
    for (int r = 0; r < 16; ++r) oacc[dg][r] = 0.f;
  float l_run = 0.f;

  // prologue: tile 0
#pragma unroll
  for (int i = 0; i < 4; ++i) gload16(K + offK[i], lds + kbase + i * 1024);
#pragma unroll
  for (int i = 0; i < 4; ++i) gload16(V + offV[i], lds + vbase + i * 1024);

  const int krow = wk * 32 + c31;
  const int rxk = krow & 15;
  const int rxv = c31 & 7;

#pragma unroll 1
  for (int kt = 0; kt < NT; ++kt) {
    char* buf = lds + (kt & 1) * 32768;
    if (kt + 1 < NT) {
      char* nbuf = lds + ((kt + 1) & 1) * 32768;
#pragma unroll
      for (int i = 0; i < 4; ++i) {
        offK[i] += (unsigned)(KVB * HDIM);
        gload16(K + offK[i], nbuf + kbase + i * 1024);
      }
#pragma unroll
      for (int i = 0; i < 4; ++i) {
        offV[i] += (unsigned)KVB;
        gload16(V + offV[i], nbuf + vbase + i * 1024);
      }
      asm volatile("s_waitcnt vmcnt(8)" ::: "memory");  // tile kt landed
    } else {
      asm volatile("s_waitcnt vmcnt(0)" ::: "memory");
    }
    __builtin_amdgcn_s_barrier();

    const char* Kt = buf;
    const char* Vt = buf + 16384;

    // S^T = mfma(K, Q): D[kpos][q], lane = q, regs = kpos (wave's 32 kpos).
    f32x16 s;
#pragma unroll
    for (int r = 0; r < 16; ++r) s[r] = 0.f;
    __builtin_amdgcn_s_setprio(1);
    {
      const char* kr = Kt + krow * 256;
#pragma unroll
      for (int cs = 0; cs < 8; ++cs) {
        bf16x8 kf = *reinterpret_cast<const bf16x8*>(
            kr + (((cs * 2 + hi) ^ rxk) * 16));
        s = mfma32(kf, qf[cs], s);
      }
    }
    __builtin_amdgcn_s_setprio(0);

    // V-fragment prefetch: issue all 8 ds_reads now so their latency hides
    // under the softmax VALU chain below.
    bf16x8 vf[8];
#pragma unroll
    for (int dg = 0; dg < 4; ++dg) {
      const char* vr = Vt + (dg * 32 + c31) * 128;
      vf[2 * dg + 0] = *reinterpret_cast<const bf16x8*>(
          vr + (((wk * 4 + 0 + hi) ^ rxv) * 16));
      vf[2 * dg + 1] = *reinterpret_cast<const bf16x8*>(
          vr + (((wk * 4 + 2 + hi) ^ rxv) * 16));
    }

    // Max-free softmax: P = exp2(S') unnormalized (Q pre-scaled by log2e).
#pragma unroll
    for (int r = 0; r < 16; ++r) s[r] = __builtin_amdgcn_exp2f(s[r]);
    {  // tree sum (chain depth 4)
      float a0 = s[0] + s[1], a1 = s[2] + s[3], a2 = s[4] + s[5], a3 = s[6] + s[7];
      float a4 = s[8] + s[9], a5 = s[10] + s[11], a6 = s[12] + s[13], a7 = s[14] + s[15];
      float b0 = a0 + a1, b1 = a2 + a3, b2 = a4 + a5, b3 = a6 + a7;
      l_run += (b0 + b1) + (b2 + b3);
    }

    // P -> bf16 A-fragments in-register.
    unsigned w0 = cvtpk(s[0], s[1]);
    unsigned w1 = cvtpk(s[2], s[3]);
    unsigned w2 = cvtpk(s[4], s[5]);
    unsigned w3 = cvtpk(s[6], s[7]);
    unsigned w4 = cvtpk(s[8], s[9]);
    unsigned w5 = cvtpk(s[10], s[11]);
    unsigned w6 = cvtpk(s[12], s[13]);
    unsigned w7 = cvtpk(s[14], s[15]);
    pswap(w0, w2); pswap(w1, w3); pswap(w4, w6); pswap(w5, w7);
    u32x4 pw0 = {w0, w1, w2, w3};
    u32x4 pw1 = {w4, w5, w6, w7};
    bf16x8 pa0 = __builtin_bit_cast(bf16x8, pw0);
    bf16x8 pa1 = __builtin_bit_cast(bf16x8, pw1);

    // PV: O[q][h] += P[q][kpos] V[kpos][h]  (vf already in registers).
    __builtin_amdgcn_s_setprio(1);
#pragma unroll
    for (int dg = 0; dg < 4; ++dg) {
      oacc[dg] = mfma32(pa0, vf[2 * dg + 0], oacc[dg]);
      oacc[dg] = mfma32(pa1, vf[2 * dg + 1], oacc[dg]);
    }
    __builtin_amdgcn_s_setprio(0);
    __builtin_amdgcn_s_barrier();  // all waves done reading buf
  }

  // ---- split-k-2 merge (wk pairs). Tile buffers dead; reuse LDS.
  l_run += __shfl_xor(l_run, 32);
  float* O1 = (float*)lds;             // [wm][dg][r][64 lanes] 2 x 16 KB
  float* L1 = (float*)(lds + 32768);   // [2][32]
  if (wk == 1) {
#pragma unroll
    for (int dg = 0; dg < 4; ++dg)
#pragma unroll
      for (int r = 0; r < 16; ++r)
        O1[wm * 4096 + (dg * 16 + r) * 64 + l] = oacc[dg][r];
    if (l < 32) L1[wm * 32 + c31] = l_run;
  }
  __syncthreads();
  if (wk == 0) {
    float linv = 1.0f / (l_run + L1[wm * 32 + c31]);
    int ibits = __builtin_bit_cast(int, linv);
#pragma unroll
    for (int dg = 0; dg < 4; ++dg) {
      int h = dg * 32 + c31;
#pragma unroll
      for (int r = 0; r < 16; ++r) {
        int crow = (r & 3) + 8 * (r >> 2) + 4 * hi;
        float fr = __builtin_bit_cast(
            float, __builtin_amdgcn_ds_bpermute(crow * 4, ibits));
        float val = (oacc[dg][r] + O1[wm * 4096 + (dg * 16 + r) * 64 + l]) * fr;
        int n = q0 + wm * 32 + crow;
        O[((size_t)b * NDIM + n) * HDIM + h] = (bf16)val;
      }
    }
  }
}

// ---------------------------------------------------------------------------
// Kernel 3: out = Wf @ O + bf + x (unchanged; at HBM roofline ~12 us)
// ---------------------------------------------------------------------------
__global__ __launch_bounds__(256) void k3_proj(
    const bf16* __restrict__ O, const float* __restrict__ Wf,
    const float* __restrict__ bfv, const float* __restrict__ x,
    float* __restrict__ out) {
  __shared__ char lds[49152];
  char* Wt = lds;
  char* Ot = lds + 32768;

  const int t = threadIdx.x;
  const int l = t & 63;
  const int w = t >> 6;
  const int b = blockIdx.x >> 5;
  const int n0 = (blockIdx.x & 31) * 64;

#pragma unroll
  for (int pass = 0; pass < 4; ++pass) {
    int n = pass * 16 + (t >> 4);
    int hq = t & 15;
    uint4 d = *reinterpret_cast<const uint4*>(
        O + (size_t)(b * NDIM + n0 + n) * HDIM + hq * 8);
    *reinterpret_cast<uint4*>(Ot + swz256(n, hq * 16)) = d;
  }

#pragma unroll 1
  for (int ch = 0; ch < 2; ++ch) {
    __syncthreads();
#pragma unroll
    for (int pass = 0; pass < 8; ++pass) {
      int cl = pass * 16 + (t >> 4);
      int hq = t & 15;
      const float* src = Wf + (size_t)(ch * 128 + cl) * HDIM + hq * 8;
      float4 v0 = *reinterpret_cast<const float4*>(src);
      float4 v1 = *reinterpret_cast<const float4*>(src + 4);
      *reinterpret_cast<bf16x8*>(Wt + swz256(cl, hq * 16)) = cvt8(v0, v1);
    }
    __syncthreads();

    f32x4 acc[2][4];
#pragma unroll
    for (int i = 0; i < 2; ++i)
#pragma unroll
      for (int j = 0; j < 4; ++j) acc[i][j] = f32x4{0.f, 0.f, 0.f, 0.f};

#pragma unroll
    for (int ks = 0; ks < 4; ++ks) {
      int cb = ks * 64 + (l >> 4) * 16;
      bf16x8 a0 = *reinterpret_cast<const bf16x8*>(
          Wt + swz256(w * 32 + (l & 15), cb));
      bf16x8 a1 = *reinterpret_cast<const bf16x8*>(
          Wt + swz256(w * 32 + 16 + (l & 15), cb));
#pragma unroll
      for (int nf = 0; nf < 4; ++nf) {
        bf16x8 bb = *reinterpret_cast<const bf16x8*>(
            Ot + swz256(nf * 16 + (l & 15), cb));
        acc[0][nf] = mfma16(a0, bb, acc[0][nf]);
        acc[1][nf] = mfma16(a1, bb, acc[1][nf]);
      }
    }

#pragma unroll
    for (int mf = 0; mf < 2; ++mf)
#pragma unroll
      for (int nf = 0; nf < 4; ++nf)
#pragma unroll
        for (int r = 0; r < 4; ++r) {
          int c = ch * 128 + w * 32 + mf * 16 + (l >> 4) * 4 + r;
          int n = n0 + nf * 16 + (l & 15);
          size_t idx = (size_t)(b * CDIM + c) * NDIM + n;
          out[idx] = acc[mf][nf][r] + bfv[c] + x[idx];
        }
  }
}

extern "C" void kernel_launch(void* const* d_in, const int* in_sizes, int n_in,
                              void* d_out, int out_size, void* d_ws,
                              size_t ws_size, hipStream_t stream) {
  (void)in_sizes; (void)n_in; (void)out_size;
  const float* x = (const float*)d_in[0];
  const float* Wq = (const float*)d_in[1];
  const float* bq = (const float*)d_in[2];
  const float* Wk = (const float*)d_in[3];
  const float* bk = (const float*)d_in[4];
  const float* Wv = (const float*)d_in[5];
  const float* bv = (const float*)d_in[6];
  const float* Wf = (const float*)d_in[7];
  const float* bfv = (const float*)d_in[8];
  float* out = (float*)d_out;

  if (ws_size < (24u << 20)) return;
  char* ws = (char*)d_ws;
  bf16* Qb = (bf16*)(ws);                  // 8 MB [B][N][H]; reused as O
  bf16* Kb = (bf16*)(ws + (8u << 20));     // 8 MB [B][N][H]
  bf16* Vb = (bf16*)(ws + (16u << 20));    // 8 MB [B][H][N]

  const unsigned k2_lds = 65536;  // 2 x 32 KB double buffer (merge reuses it)
  hipFuncSetAttribute(reinterpret_cast<const void*>(k2_attn),
                      hipFuncAttributeMaxDynamicSharedMemorySize, (int)k2_lds);

  k1_qkv<<<512, 256, 0, stream>>>(x, Wq, bq, Wk, bk, Wv, bv, Qb, Kb, Vb);
  k2_attn<<<512, 256, k2_lds, stream>>>(Qb, Kb, Vb, Qb);
  k3_proj<<<512, 256, 0, stream>>>(Qb, Wf, bfv, x, out);
}

// Round 11
// 91.692 us; speedup vs baseline: 1.4557x; 1.0766x over previous
//
#include <hip/hip_runtime.h>
#include <hip/hip_bf16.h>

#define BATCH 16
#define CDIM 256
#define NDIM 2048
#define HDIM 128
#define KVB 64
#define NT (NDIM / KVB)

typedef __bf16 bf16;
typedef float f32x4 __attribute__((ext_vector_type(4)));
typedef float f32x16 __attribute__((ext_vector_type(16)));
typedef bf16 bf16x8 __attribute__((ext_vector_type(8)));
typedef unsigned int u32x4 __attribute__((ext_vector_type(4)));
typedef unsigned int u32x2 __attribute__((ext_vector_type(2)));

#define LOG2E 1.4426950408889634f

__device__ __forceinline__ int swz512(int row, int colbyte) {
  return row * 512 + (colbyte ^ ((row & 15) << 4));
}
__device__ __forceinline__ int swz256(int row, int colbyte) {
  return row * 256 + (colbyte ^ ((row & 7) << 4));
}

__device__ __forceinline__ f32x4 mfma16(bf16x8 a, bf16x8 b, f32x4 c) {
  return __builtin_amdgcn_mfma_f32_16x16x32_bf16(a, b, c, 0, 0, 0);
}
__device__ __forceinline__ f32x16 mfma32(bf16x8 a, bf16x8 b, f32x16 c) {
  return __builtin_amdgcn_mfma_f32_32x32x16_bf16(a, b, c, 0, 0, 0);
}

__device__ __forceinline__ unsigned cvtpk(float lo, float hi) {
  unsigned r;
  asm("v_cvt_pk_bf16_f32 %0, %1, %2" : "=v"(r) : "v"(lo), "v"(hi));
  return r;
}
__device__ __forceinline__ void pswap(unsigned &a, unsigned &b) {
  asm volatile("v_permlane32_swap_b32 %0, %1" : "+v"(a), "+v"(b));
}

__device__ __forceinline__ void gload16(const bf16* g, char* l) {
  __builtin_amdgcn_global_load_lds(
      (const __attribute__((address_space(1))) void*)g,
      (__attribute__((address_space(3))) void*)l, 16, 0, 0);
}

__device__ __forceinline__ bf16x8 cvt8(float4 a, float4 b) {
  bf16x8 o;
  o[0] = (bf16)a.x; o[1] = (bf16)a.y; o[2] = (bf16)a.z; o[3] = (bf16)a.w;
  o[4] = (bf16)b.x; o[5] = (bf16)b.y; o[6] = (bf16)b.z; o[7] = (bf16)b.w;
  return o;
}

// ---------------------------------------------------------------------------
// Kernel 0: pack Wq/Wk/Wv -> bf16 row-major Wpk[p][128 h][256 c].
// ---------------------------------------------------------------------------
__global__ __launch_bounds__(256) void k0_pack(
    const float* __restrict__ Wq, const float* __restrict__ Wk,
    const float* __restrict__ Wv, bf16* __restrict__ Wpk) {
  int g = blockIdx.x * 256 + threadIdx.x;  // 0..12287
  int p = g >> 12;
  int e = (g & 4095) * 8;
  const float* W = (p == 0) ? Wq : (p == 1 ? Wk : Wv);
  float4 v0 = *reinterpret_cast<const float4*>(W + e);
  float4 v1 = *reinterpret_cast<const float4*>(W + e + 4);
  *reinterpret_cast<bf16x8*>(Wpk + p * 32768 + e) = cvt8(v0, v1);
}

// ---------------------------------------------------------------------------
// Kernel 1: fused QKV projection, k2-style pipelined W staging:
// 12 rounds of 16KB bf16 W-quarters via global_load_lds, double-buffered,
// counted vmcnt(4) (next quarter in flight across the barrier). xT staged
// via in-register shfl transpose. LDS 64KB -> 2 blocks/CU.
// grid 512 = (b:16) x (ntile:32, 64 cols), 256 thr = 4 waves.
// ---------------------------------------------------------------------------
__global__ __launch_bounds__(256) void k1_qkv(
    const float* __restrict__ x, const bf16* __restrict__ Wpk,
    const float* __restrict__ bq, const float* __restrict__ bk,
    const float* __restrict__ bv,
    bf16* __restrict__ Qo, bf16* __restrict__ Ko, bf16* __restrict__ Vo) {
  __shared__ char lds_[65536];
  char* xT = lds_;                     // [64 n][256 c] bf16 swz512 (32 KB)
  char* wb0 = lds_ + 32768;            // W quarter buf 0 (16 KB)
  char* wb1 = lds_ + 49152;            // W quarter buf 1 (16 KB)

  const int t = threadIdx.x;
  const int l = t & 63;
  const int w = t >> 6;
  const int q = (l >> 4) & 3;
  const int b = blockIdx.x >> 5;
  const int n0 = (blockIdx.x & 31) * 64;

  // W staging geometry: rows h = i*32 + w*8 + (l>>3), slot = l&7 (16B of 8
  // bf16). LDS dest linear (wave base + lane*16); source slot XOR'd with
  // (h&7) = (l>>3)  [rule #21: swizzle on source + on read, LDS linear].
  const int lane_off = (l >> 3) * 256 + (((l & 7) ^ (l >> 3)) * 8);  // elems

  // Issue round-0 W loads first (latency overlaps the xT transpose below).
#pragma unroll
  for (int i = 0; i < 4; ++i)
    gload16(Wpk + 0 * 32768 + 0 * 64 + i * 8192 + w * 2048 + lane_off,
            wb0 + i * 4096 + w * 1024);

  // Stage xT via in-register 4x4 shfl transpose.
#pragma unroll
  for (int p = 0; p < 16; ++p) {
    int c = w * 64 + p * 4 + q;
    float4 v = *reinterpret_cast<const float4*>(
        x + (size_t)(b * CDIM + c) * NDIM + n0 + (l & 15) * 4);
    float t0 = __shfl_xor(v.x, 16), t1 = __shfl_xor(v.y, 16);
    float t2 = __shfl_xor(v.z, 16), t3 = __shfl_xor(v.w, 16);
    float4 wv;
    if ((q & 1) == 0) wv = make_float4(v.x, t0, v.z, t2);
    else              wv = make_float4(t1, v.y, t3, v.w);
    float s0 = __shfl_xor(wv.x, 32), s1 = __shfl_xor(wv.y, 32);
    float s2 = __shfl_xor(wv.z, 32), s3 = __shfl_xor(wv.w, 32);
    float4 z;
    if ((q & 2) == 0) z = make_float4(wv.x, wv.y, s0, s1);
    else              z = make_float4(s2, s3, wv.z, wv.w);
    u32x2 pk = {cvtpk(z.x, z.y), cvtpk(z.z, z.w)};
    int n = (l & 15) * 4 + q;
    int slot = w * 8 + (p >> 1);
    *reinterpret_cast<u32x2*>(
        xT + n * 512 + ((slot ^ (n & 15)) * 16 + (p & 1) * 8)) = pk;
  }
  asm volatile("s_waitcnt lgkmcnt(0)" ::: "memory");  // xT writes committed

  f32x4 acc[8];
  const float* bias_p[3] = {bq, bk, bv};

#pragma unroll 1
  for (int r = 0; r < 12; ++r) {
    const int p = r >> 2, kq = r & 3;
    char* wb = (r & 1) ? wb1 : wb0;
    if ((r & 3) == 0) {
#pragma unroll
      for (int i = 0; i < 8; ++i) acc[i] = f32x4{0.f, 0.f, 0.f, 0.f};
    }
    // Issue round r+1 into the other buffer (its readers finished before
    // the bottom barrier of round r-1).
    if (r + 1 < 12) {
      const int p1 = (r + 1) >> 2, kq1 = (r + 1) & 3;
      char* nwb = (r & 1) ? wb0 : wb1;
      const bf16* src = Wpk + p1 * 32768 + kq1 * 64 + w * 2048 + lane_off;
#pragma unroll
      for (int i = 0; i < 4; ++i)
        gload16(src + i * 8192, nwb + i * 4096 + w * 1024);
      asm volatile("s_waitcnt vmcnt(4)" ::: "memory");  // round r landed
    } else {
      asm volatile("s_waitcnt vmcnt(0)" ::: "memory");
    }
    __builtin_amdgcn_s_barrier();

    if (p < 2) {
      // D[n][h] = xT * W^T : A rows = n (wave owns 16), B cols = h (8 frags)
#pragma unroll
      for (int ks = 0; ks < 2; ++ks) {
        int cb = kq * 128 + ks * 64 + (l >> 4) * 16;
        bf16x8 a = *reinterpret_cast<const bf16x8*>(
            xT + swz512(w * 16 + (l & 15), cb));
        int slot = ((ks * 4 + (l >> 4)) ^ (l & 7)) * 16;
#pragma unroll
        for (int nf = 0; nf < 8; ++nf) {
          bf16x8 bb = *reinterpret_cast<const bf16x8*>(
              wb + (nf * 16 + (l & 15)) * 128 + slot);
          acc[nf] = mfma16(a, bb, acc[nf]);
        }
      }
    } else {
      // V: D[h][n] = W * x : A rows = h (wave owns 32), B cols = n (4 frags)
#pragma unroll
      for (int ks = 0; ks < 2; ++ks) {
        int slot = ((ks * 4 + (l >> 4)) ^ (l & 7)) * 16;
        bf16x8 a0 = *reinterpret_cast<const bf16x8*>(
            wb + (w * 32 + (l & 15)) * 128 + slot);
        bf16x8 a1 = *reinterpret_cast<const bf16x8*>(
            wb + (w * 32 + 16 + (l & 15)) * 128 + slot);
        int cb = kq * 128 + ks * 64 + (l >> 4) * 16;
#pragma unroll
        for (int nf4 = 0; nf4 < 4; ++nf4) {
          bf16x8 bx = *reinterpret_cast<const bf16x8*>(
              xT + swz512(nf4 * 16 + (l & 15), cb));
          acc[nf4] = mfma16(a0, bx, acc[nf4]);
          acc[4 + nf4] = mfma16(a1, bx, acc[4 + nf4]);
        }
      }
    }

    // Epilogue at the last quarter of each projection.
    if ((r & 3) == 3) {
      if (p < 2) {
        bf16* dst = (p == 0) ? Qo : Ko;
        const float scale = (p == 0) ? LOG2E : 1.0f;  // Q pre-scaled for exp2
#pragma unroll
        for (int nf = 0; nf < 8; ++nf) {
          float bias = bias_p[p][nf * 16 + (l & 15)];
#pragma unroll
          for (int rr = 0; rr < 4; ++rr) {
            int n = n0 + w * 16 + (l >> 4) * 4 + rr;
            int h = nf * 16 + (l & 15);
            dst[(size_t)(b * NDIM + n) * HDIM + h] =
                (bf16)((acc[nf][rr] + bias) * scale);
          }
        }
      } else {
#pragma unroll
        for (int mf = 0; mf < 2; ++mf)
#pragma unroll
          for (int nf4 = 0; nf4 < 4; ++nf4)
#pragma unroll
            for (int rr = 0; rr < 4; ++rr) {
              int h = w * 32 + mf * 16 + (l >> 4) * 4 + rr;
              int n = n0 + nf4 * 16 + (l & 15);
              Vo[(size_t)(b * HDIM + h) * NDIM + n] =
                  (bf16)(acc[mf * 4 + nf4][rr] + bv[h]);
            }
      }
    }
    __builtin_amdgcn_s_barrier();  // all waves done reading wb
  }
}

// ---------------------------------------------------------------------------
// Kernel 2: flash attention (R10, frozen control): exp2-direct softmax,
// KVB=64 dbuf (2 independent blocks/CU), global_load_lds + counted vmcnt(8),
// in-register P, split-k-2 merge. grid 512, 256 thr.
// ---------------------------------------------------------------------------
__global__ __launch_bounds__(256, 2) void k2_attn(
    const bf16* __restrict__ Q, const bf16* __restrict__ K,
    const bf16* __restrict__ V, bf16* __restrict__ O) {
  extern __shared__ char lds[];

  const int t = threadIdx.x;
  const int l = t & 63;
  const int w = t >> 6;
  const int wm = w & 1;
  const int wk = w >> 1;
  const int hi = l >> 5;
  const int c31 = l & 31;

  const int pid = blockIdx.x;
  const int b = (pid & 7) * 2 + ((pid >> 3) >> 5);
  const int q0 = ((pid >> 3) & 31) * 64;

  bf16x8 qf[8];
  {
    const bf16* qb = Q + ((size_t)b * NDIM + q0 + wm * 32 + c31) * HDIM + hi * 8;
#pragma unroll
    for (int cs = 0; cs < 8; ++cs)
      qf[cs] = *reinterpret_cast<const bf16x8*>(qb + cs * 16);
  }

  unsigned offK[4], offV[4];
  {
    const int krow = w * 16 + (l >> 4);
    const int kslot = l & 15;
#pragma unroll
    for (int i = 0; i < 4; ++i) {
      int r = krow + i * 4;
      offK[i] = (unsigned)((b * NDIM + r) * HDIM + (kslot ^ (r & 15)) * 8);
    }
    const int vrow = w * 32 + (l >> 3);
    const int vslot = l & 7;
#pragma unroll
    for (int i = 0; i < 4; ++i) {
      int r = vrow + i * 8;
      offV[i] = (unsigned)((b * HDIM + r) * NDIM + (vslot ^ (r & 7)) * 8);
    }
  }
  const int kbase = w * 4096;
  const int vbase = 16384 + w * 4096;

  f32x16 oacc[4];
#pragma unroll
  for (int dg = 0; dg < 4; ++dg)
#pragma unroll
    for (int r = 0; r < 16; ++r) oacc[dg][r] = 0.f;
  float l_run = 0.f;

#pragma unroll
  for (int i = 0; i < 4; ++i) gload16(K + offK[i], lds + kbase + i * 1024);
#pragma unroll
  for (int i = 0; i < 4; ++i) gload16(V + offV[i], lds + vbase + i * 1024);

  const int krow = wk * 32 + c31;
  const int rxk = krow & 15;
  const int rxv = c31 & 7;

#pragma unroll 1
  for (int kt = 0; kt < NT; ++kt) {
    char* buf = lds + (kt & 1) * 32768;
    if (kt + 1 < NT) {
      char* nbuf = lds + ((kt + 1) & 1) * 32768;
#pragma unroll
      for (int i = 0; i < 4; ++i) {
        offK[i] += (unsigned)(KVB * HDIM);
        gload16(K + offK[i], nbuf + kbase + i * 1024);
      }
#pragma unroll
      for (int i = 0; i < 4; ++i) {
        offV[i] += (unsigned)KVB;
        gload16(V + offV[i], nbuf + vbase + i * 1024);
      }
      asm volatile("s_waitcnt vmcnt(8)" ::: "memory");
    } else {
      asm volatile("s_waitcnt vmcnt(0)" ::: "memory");
    }
    __builtin_amdgcn_s_barrier();

    const char* Kt = buf;
    const char* Vt = buf + 16384;

    f32x16 s;
#pragma unroll
    for (int r = 0; r < 16; ++r) s[r] = 0.f;
    __builtin_amdgcn_s_setprio(1);
    {
      const char* kr = Kt + krow * 256;
#pragma unroll
      for (int cs = 0; cs < 8; ++cs) {
        bf16x8 kf = *reinterpret_cast<const bf16x8*>(
            kr + (((cs * 2 + hi) ^ rxk) * 16));
        s = mfma32(kf, qf[cs], s);
      }
    }
    __builtin_amdgcn_s_setprio(0);

    bf16x8 vf[8];
#pragma unroll
    for (int dg = 0; dg < 4; ++dg) {
      const char* vr = Vt + (dg * 32 + c31) * 128;
      vf[2 * dg + 0] = *reinterpret_cast<const bf16x8*>(
          vr + (((wk * 4 + 0 + hi) ^ rxv) * 16));
      vf[2 * dg + 1] = *reinterpret_cast<const bf16x8*>(
          vr + (((wk * 4 + 2 + hi) ^ rxv) * 16));
    }

#pragma unroll
    for (int r = 0; r < 16; ++r) s[r] = __builtin_amdgcn_exp2f(s[r]);
    {
      float a0 = s[0] + s[1], a1 = s[2] + s[3], a2 = s[4] + s[5], a3 = s[6] + s[7];
      float a4 = s[8] + s[9], a5 = s[10] + s[11], a6 = s[12] + s[13], a7 = s[14] + s[15];
      float b0 = a0 + a1, b1 = a2 + a3, b2 = a4 + a5, b3 = a6 + a7;
      l_run += (b0 + b1) + (b2 + b3);
    }

    unsigned w0 = cvtpk(s[0], s[1]);
    unsigned w1 = cvtpk(s[2], s[3]);
    unsigned w2 = cvtpk(s[4], s[5]);
    unsigned w3 = cvtpk(s[6], s[7]);
    unsigned w4 = cvtpk(s[8], s[9]);
    unsigned w5 = cvtpk(s[10], s[11]);
    unsigned w6 = cvtpk(s[12], s[13]);
    unsigned w7 = cvtpk(s[14], s[15]);
    pswap(w0, w2); pswap(w1, w3); pswap(w4, w6); pswap(w5, w7);
    u32x4 pw0 = {w0, w1, w2, w3};
    u32x4 pw1 = {w4, w5, w6, w7};
    bf16x8 pa0 = __builtin_bit_cast(bf16x8, pw0);
    bf16x8 pa1 = __builtin_bit_cast(bf16x8, pw1);

    __builtin_amdgcn_s_setprio(1);
#pragma unroll
    for (int dg = 0; dg < 4; ++dg) {
      oacc[dg] = mfma32(pa0, vf[2 * dg + 0], oacc[dg]);
      oacc[dg] = mfma32(pa1, vf[2 * dg + 1], oacc[dg]);
    }
    __builtin_amdgcn_s_setprio(0);
    __builtin_amdgcn_s_barrier();
  }

  l_run += __shfl_xor(l_run, 32);
  float* O1 = (float*)lds;
  float* L1 = (float*)(lds + 32768);
  if (wk == 1) {
#pragma unroll
    for (int dg = 0; dg < 4; ++dg)
#pragma unroll
      for (int r = 0; r < 16; ++r)
        O1[wm * 4096 + (dg * 16 + r) * 64 + l] = oacc[dg][r];
    if (l < 32) L1[wm * 32 + c31] = l_run;
  }
  __syncthreads();
  if (wk == 0) {
    float linv = 1.0f / (l_run + L1[wm * 32 + c31]);
    int ibits = __builtin_bit_cast(int, linv);
#pragma unroll
    for (int dg = 0; dg < 4; ++dg) {
      int h = dg * 32 + c31;
#pragma unroll
      for (int r = 0; r < 16; ++r) {
        int crow = (r & 3) + 8 * (r >> 2) + 4 * hi;
        float fr = __builtin_bit_cast(
            float, __builtin_amdgcn_ds_bpermute(crow * 4, ibits));
        float val = (oacc[dg][r] + O1[wm * 4096 + (dg * 16 + r) * 64 + l]) * fr;
        int n = q0 + wm * 32 + crow;
        O[((size_t)b * NDIM + n) * HDIM + h] = (bf16)val;
      }
    }
  }
}

// ---------------------------------------------------------------------------
// Kernel 3: out = Wf @ O + bf + x (unchanged; near HBM roofline)
// ---------------------------------------------------------------------------
__global__ __launch_bounds__(256) void k3_proj(
    const bf16* __restrict__ O, const float* __restrict__ Wf,
    const float* __restrict__ bfv, const float* __restrict__ x,
    float* __restrict__ out) {
  __shared__ char lds[49152];
  char* Wt = lds;
  char* Ot = lds + 32768;

  const int t = threadIdx.x;
  const int l = t & 63;
  const int w = t >> 6;
  const int b = blockIdx.x >> 5;
  const int n0 = (blockIdx.x & 31) * 64;

#pragma unroll
  for (int pass = 0; pass < 4; ++pass) {
    int n = pass * 16 + (t >> 4);
    int hq = t & 15;
    uint4 d = *reinterpret_cast<const uint4*>(
        O + (size_t)(b * NDIM + n0 + n) * HDIM + hq * 8);
    *reinterpret_cast<uint4*>(Ot + swz256(n, hq * 16)) = d;
  }

#pragma unroll 1
  for (int ch = 0; ch < 2; ++ch) {
    __syncthreads();
#pragma unroll
    for (int pass = 0; pass < 8; ++pass) {
      int cl = pass * 16 + (t >> 4);
      int hq = t & 15;
      const float* src = Wf + (size_t)(ch * 128 + cl) * HDIM + hq * 8;
      float4 v0 = *reinterpret_cast<const float4*>(src);
      float4 v1 = *reinterpret_cast<const float4*>(src + 4);
      *reinterpret_cast<bf16x8*>(Wt + swz256(cl, hq * 16)) = cvt8(v0, v1);
    }
    __syncthreads();

    f32x4 acc[2][4];
#pragma unroll
    for (int i = 0; i < 2; ++i)
#pragma unroll
      for (int j = 0; j < 4; ++j) acc[i][j] = f32x4{0.f, 0.f, 0.f, 0.f};

#pragma unroll
    for (int ks = 0; ks < 4; ++ks) {
      int cb = ks * 64 + (l >> 4) * 16;
      bf16x8 a0 = *reinterpret_cast<const bf16x8*>(
          Wt + swz256(w * 32 + (l & 15), cb));
      bf16x8 a1 = *reinterpret_cast<const bf16x8*>(
          Wt + swz256(w * 32 + 16 + (l & 15), cb));
#pragma unroll
      for (int nf = 0; nf < 4; ++nf) {
        bf16x8 bb = *reinterpret_cast<const bf16x8*>(
            Ot + swz256(nf * 16 + (l & 15), cb));
        acc[0][nf] = mfma16(a0, bb, acc[0][nf]);
        acc[1][nf] = mfma16(a1, bb, acc[1][nf]);
      }
    }

#pragma unroll
    for (int mf = 0; mf < 2; ++mf)
#pragma unroll
      for (int nf = 0; nf < 4; ++nf)
#pragma unroll
        for (int r = 0; r < 4; ++r) {
          int c = ch * 128 + w * 32 + mf * 16 + (l >> 4) * 4 + r;
          int n = n0 + nf * 16 + (l & 15);
          size_t idx = (size_t)(b * CDIM + c) * NDIM + n;
          out[idx] = acc[mf][nf][r] + bfv[c] + x[idx];
        }
  }
}

extern "C" void kernel_launch(void* const* d_in, const int* in_sizes, int n_in,
                              void* d_out, int out_size, void* d_ws,
                              size_t ws_size, hipStream_t stream) {
  (void)in_sizes; (void)n_in;
  const float* x = (const float*)d_in[0];
  const float* Wq = (const float*)d_in[1];
  const float* bq = (const float*)d_in[2];
  const float* Wk = (const float*)d_in[3];
  const float* bk = (const float*)d_in[4];
  const float* Wv = (const float*)d_in[5];
  const float* bv = (const float*)d_in[6];
  const float* Wf = (const float*)d_in[7];
  const float* bfv = (const float*)d_in[8];
  float* out = (float*)d_out;

  if (ws_size < (24u << 20)) return;
  char* ws = (char*)d_ws;
  bf16* Qb = (bf16*)(ws);                  // 8 MB [B][N][H]; reused as O
  bf16* Kb = (bf16*)(ws + (8u << 20));     // 8 MB [B][N][H]
  bf16* Vb = (bf16*)(ws + (16u << 20));    // 8 MB [B][H][N]

  // Packed bf16 W (192 KB) in d_out's tail; k3 overwrites it afterwards.
  const size_t out_bytes = (size_t)out_size * 4;
  bf16* Wpk = (bf16*)((char*)d_out + out_bytes - 196608);

  const unsigned k2_lds = 65536;
  hipFuncSetAttribute(reinterpret_cast<const void*>(k2_attn),
                      hipFuncAttributeMaxDynamicSharedMemorySize, (int)k2_lds);

  k0_pack<<<48, 256, 0, stream>>>(Wq, Wk, Wv, Wpk);
  k1_qkv<<<512, 256, 0, stream>>>(x, Wpk, bq, bk, bv, Qb, Kb, Vb);
  k2_attn<<<512, 256, k2_lds, stream>>>(Qb, Kb, Vb, Qb);
  k3_proj<<<512, 256, 0, stream>>>(Qb, Wf, bfv, x, out);
}

// Round 12
// 89.757 us; speedup vs baseline: 1.4871x; 1.0216x over previous
//
#include <hip/hip_runtime.h>
#include <hip/hip_bf16.h>

#define BATCH 16
#define CDIM 256
#define NDIM 2048
#define HDIM 128
#define KVB 64
#define NT (NDIM / KVB)

typedef __bf16 bf16;
typedef float f32x4 __attribute__((ext_vector_type(4)));
typedef float f32x16 __attribute__((ext_vector_type(16)));
typedef bf16 bf16x8 __attribute__((ext_vector_type(8)));
typedef unsigned int u32x4 __attribute__((ext_vector_type(4)));
typedef unsigned int u32x2 __attribute__((ext_vector_type(2)));

#define LOG2E 1.4426950408889634f

__device__ __forceinline__ int swz512(int row, int colbyte) {
  return row * 512 + (colbyte ^ ((row & 15) << 4));
}
__device__ __forceinline__ int swz256(int row, int colbyte) {
  return row * 256 + (colbyte ^ ((row & 7) << 4));
}

__device__ __forceinline__ f32x4 mfma16(bf16x8 a, bf16x8 b, f32x4 c) {
  return __builtin_amdgcn_mfma_f32_16x16x32_bf16(a, b, c, 0, 0, 0);
}
__device__ __forceinline__ f32x16 mfma32(bf16x8 a, bf16x8 b, f32x16 c) {
  return __builtin_amdgcn_mfma_f32_32x32x16_bf16(a, b, c, 0, 0, 0);
}

__device__ __forceinline__ unsigned cvtpk(float lo, float hi) {
  unsigned r;
  asm("v_cvt_pk_bf16_f32 %0, %1, %2" : "=v"(r) : "v"(lo), "v"(hi));
  return r;
}
__device__ __forceinline__ void pswap(unsigned &a, unsigned &b) {
  asm volatile("v_permlane32_swap_b32 %0, %1" : "+v"(a), "+v"(b));
}

__device__ __forceinline__ void gload16(const bf16* g, char* l) {
  __builtin_amdgcn_global_load_lds(
      (const __attribute__((address_space(1))) void*)g,
      (__attribute__((address_space(3))) void*)l, 16, 0, 0);
}

__device__ __forceinline__ bf16x8 cvt8(float4 a, float4 b) {
  bf16x8 o;
  o[0] = (bf16)a.x; o[1] = (bf16)a.y; o[2] = (bf16)a.z; o[3] = (bf16)a.w;
  o[4] = (bf16)b.x; o[5] = (bf16)b.y; o[6] = (bf16)b.z; o[7] = (bf16)b.w;
  return o;
}

// ---------------------------------------------------------------------------
// Kernel 0: pack Wq/Wk/Wv -> bf16 row-major Wpk[p][128 h][256 c]. (frozen)
// ---------------------------------------------------------------------------
__global__ __launch_bounds__(256) void k0_pack(
    const float* __restrict__ Wq, const float* __restrict__ Wk,
    const float* __restrict__ Wv, bf16* __restrict__ Wpk) {
  int g = blockIdx.x * 256 + threadIdx.x;  // 0..12287
  int p = g >> 12;
  int e = (g & 4095) * 8;
  const float* W = (p == 0) ? Wq : (p == 1 ? Wk : Wv);
  float4 v0 = *reinterpret_cast<const float4*>(W + e);
  float4 v1 = *reinterpret_cast<const float4*>(W + e + 4);
  *reinterpret_cast<bf16x8*>(Wpk + p * 32768 + e) = cvt8(v0, v1);
}

// ---------------------------------------------------------------------------
// Kernel 1: fused QKV projection (frozen from R11; ~at HBM floor).
// ---------------------------------------------------------------------------
__global__ __launch_bounds__(256) void k1_qkv(
    const float* __restrict__ x, const bf16* __restrict__ Wpk,
    const float* __restrict__ bq, const float* __restrict__ bk,
    const float* __restrict__ bv,
    bf16* __restrict__ Qo, bf16* __restrict__ Ko, bf16* __restrict__ Vo) {
  __shared__ char lds_[65536];
  char* xT = lds_;
  char* wb0 = lds_ + 32768;
  char* wb1 = lds_ + 49152;

  const int t = threadIdx.x;
  const int l = t & 63;
  const int w = t >> 6;
  const int q = (l >> 4) & 3;
  const int b = blockIdx.x >> 5;
  const int n0 = (blockIdx.x & 31) * 64;

  const int lane_off = (l >> 3) * 256 + (((l & 7) ^ (l >> 3)) * 8);

#pragma unroll
  for (int i = 0; i < 4; ++i)
    gload16(Wpk + i * 8192 + w * 2048 + lane_off, wb0 + i * 4096 + w * 1024);

#pragma unroll
  for (int p = 0; p < 16; ++p) {
    int c = w * 64 + p * 4 + q;
    float4 v = *reinterpret_cast<const float4*>(
        x + (size_t)(b * CDIM + c) * NDIM + n0 + (l & 15) * 4);
    float t0 = __shfl_xor(v.x, 16), t1 = __shfl_xor(v.y, 16);
    float t2 = __shfl_xor(v.z, 16), t3 = __shfl_xor(v.w, 16);
    float4 wv;
    if ((q & 1) == 0) wv = make_float4(v.x, t0, v.z, t2);
    else              wv = make_float4(t1, v.y, t3, v.w);
    float s0 = __shfl_xor(wv.x, 32), s1 = __shfl_xor(wv.y, 32);
    float s2 = __shfl_xor(wv.z, 32), s3 = __shfl_xor(wv.w, 32);
    float4 z;
    if ((q & 2) == 0) z = make_float4(wv.x, wv.y, s0, s1);
    else              z = make_float4(s2, s3, wv.z, wv.w);
    u32x2 pk = {cvtpk(z.x, z.y), cvtpk(z.z, z.w)};
    int n = (l & 15) * 4 + q;
    int slot = w * 8 + (p >> 1);
    *reinterpret_cast<u32x2*>(
        xT + n * 512 + ((slot ^ (n & 15)) * 16 + (p & 1) * 8)) = pk;
  }
  asm volatile("s_waitcnt lgkmcnt(0)" ::: "memory");

  f32x4 acc[8];
  const float* bias_p[3] = {bq, bk, bv};

#pragma unroll 1
  for (int r = 0; r < 12; ++r) {
    const int p = r >> 2, kq = r & 3;
    char* wb = (r & 1) ? wb1 : wb0;
    if ((r & 3) == 0) {
#pragma unroll
      for (int i = 0; i < 8; ++i) acc[i] = f32x4{0.f, 0.f, 0.f, 0.f};
    }
    if (r + 1 < 12) {
      const int p1 = (r + 1) >> 2, kq1 = (r + 1) & 3;
      char* nwb = (r & 1) ? wb0 : wb1;
      const bf16* src = Wpk + p1 * 32768 + kq1 * 64 + w * 2048 + lane_off;
#pragma unroll
      for (int i = 0; i < 4; ++i)
        gload16(src + i * 8192, nwb + i * 4096 + w * 1024);
      asm volatile("s_waitcnt vmcnt(4)" ::: "memory");
    } else {
      asm volatile("s_waitcnt vmcnt(0)" ::: "memory");
    }
    __builtin_amdgcn_s_barrier();

    if (p < 2) {
#pragma unroll
      for (int ks = 0; ks < 2; ++ks) {
        int cb = kq * 128 + ks * 64 + (l >> 4) * 16;
        bf16x8 a = *reinterpret_cast<const bf16x8*>(
            xT + swz512(w * 16 + (l & 15), cb));
        int slot = ((ks * 4 + (l >> 4)) ^ (l & 7)) * 16;
#pragma unroll
        for (int nf = 0; nf < 8; ++nf) {
          bf16x8 bb = *reinterpret_cast<const bf16x8*>(
              wb + (nf * 16 + (l & 15)) * 128 + slot);
          acc[nf] = mfma16(a, bb, acc[nf]);
        }
      }
    } else {
#pragma unroll
      for (int ks = 0; ks < 2; ++ks) {
        int slot = ((ks * 4 + (l >> 4)) ^ (l & 7)) * 16;
        bf16x8 a0 = *reinterpret_cast<const bf16x8*>(
            wb + (w * 32 + (l & 15)) * 128 + slot);
        bf16x8 a1 = *reinterpret_cast<const bf16x8*>(
            wb + (w * 32 + 16 + (l & 15)) * 128 + slot);
        int cb = kq * 128 + ks * 64 + (l >> 4) * 16;
#pragma unroll
        for (int nf4 = 0; nf4 < 4; ++nf4) {
          bf16x8 bx = *reinterpret_cast<const bf16x8*>(
              xT + swz512(nf4 * 16 + (l & 15), cb));
          acc[nf4] = mfma16(a0, bx, acc[nf4]);
          acc[4 + nf4] = mfma16(a1, bx, acc[4 + nf4]);
        }
      }
    }

    if ((r & 3) == 3) {
      if (p < 2) {
        bf16* dst = (p == 0) ? Qo : Ko;
        const float scale = (p == 0) ? LOG2E : 1.0f;
#pragma unroll
        for (int nf = 0; nf < 8; ++nf) {
          float bias = bias_p[p][nf * 16 + (l & 15)];
#pragma unroll
          for (int rr = 0; rr < 4; ++rr) {
            int n = n0 + w * 16 + (l >> 4) * 4 + rr;
            int h = nf * 16 + (l & 15);
            dst[(size_t)(b * NDIM + n) * HDIM + h] =
                (bf16)((acc[nf][rr] + bias) * scale);
          }
        }
      } else {
#pragma unroll
        for (int mf = 0; mf < 2; ++mf)
#pragma unroll
          for (int nf4 = 0; nf4 < 4; ++nf4)
#pragma unroll
            for (int rr = 0; rr < 4; ++rr) {
              int h = w * 32 + mf * 16 + (l >> 4) * 4 + rr;
              int n = n0 + nf4 * 16 + (l & 15);
              Vo[(size_t)(b * HDIM + h) * NDIM + n] =
                  (bf16)(acc[mf * 4 + nf4][rr] + bv[h]);
            }
      }
    }
    __builtin_amdgcn_s_barrier();
  }
}

// ---------------------------------------------------------------------------
// Kernel 2: flash attention, 1-tile software pipeline: QK^T(kt) overlaps
// softmax(kt-1)+PV(kt-1) (no data dependency -> VALU hides in MFMA shadow).
// Single barrier per tile (wait own vmcnt -> barrier -> stage next -> compute).
// Manually 2x-unrolled A/B states (no rotation movs). KVB=64 dbuf 64 KB ->
// 2 independent blocks/CU. grid 512, 256 thr = 2 q-subtiles x 2 kpos-halves.
// ---------------------------------------------------------------------------
__global__ __launch_bounds__(256, 2) void k2_attn(
    const bf16* __restrict__ Q, const bf16* __restrict__ K,
    const bf16* __restrict__ V, bf16* __restrict__ O) {
  extern __shared__ char lds[];
  // buf0 @0, buf1 @32768; each: Kt [64 kpos][256B] @0, Vt [128 d][128B] @16384

  const int t = threadIdx.x;
  const int l = t & 63;
  const int w = t >> 6;     // 0..3
  const int wm = w & 1;     // q-subtile (32 rows)
  const int wk = w >> 1;    // kpos half (32 kpos)
  const int hi = l >> 5;
  const int c31 = l & 31;

  const int pid = blockIdx.x;
  const int b = (pid & 7) * 2 + ((pid >> 3) >> 5);
  const int q0 = ((pid >> 3) & 31) * 64;

  bf16x8 qf[8];
  {
    const bf16* qb = Q + ((size_t)b * NDIM + q0 + wm * 32 + c31) * HDIM + hi * 8;
#pragma unroll
    for (int cs = 0; cs < 8; ++cs)
      qf[cs] = *reinterpret_cast<const bf16x8*>(qb + cs * 16);
  }

  unsigned offK[4], offV[4];
  {
    const int krow_s = w * 16 + (l >> 4);
    const int kslot = l & 15;
#pragma unroll
    for (int i = 0; i < 4; ++i) {
      int r = krow_s + i * 4;
      offK[i] = (unsigned)((b * NDIM + r) * HDIM + (kslot ^ (r & 15)) * 8);
    }
    const int vrow = w * 32 + (l >> 3);
    const int vslot = l & 7;
#pragma unroll
    for (int i = 0; i < 4; ++i) {
      int r = vrow + i * 8;
      offV[i] = (unsigned)((b * HDIM + r) * NDIM + (vslot ^ (r & 7)) * 8);
    }
  }
  const int kbase = w * 4096;
  const int vbase = 16384 + w * 4096;

  f32x16 oacc[4];
#pragma unroll
  for (int dg = 0; dg < 4; ++dg)
#pragma unroll
    for (int r = 0; r < 16; ++r) oacc[dg][r] = 0.f;
  float l_run = 0.f;

  const int krow = wk * 32 + c31;
  const int rxk = krow & 15;
  const int rxv = c31 & 7;

  auto stage_to = [&](char* nbuf) {
#pragma unroll
    for (int i = 0; i < 4; ++i) {
      offK[i] += (unsigned)(KVB * HDIM);
      gload16(K + offK[i], nbuf + kbase + i * 1024);
    }
#pragma unroll
    for (int i = 0; i < 4; ++i) {
      offV[i] += (unsigned)KVB;
      gload16(V + offV[i], nbuf + vbase + i * 1024);
    }
  };
  auto qkt = [&](const char* buf, f32x16& s) {
#pragma unroll
    for (int r = 0; r < 16; ++r) s[r] = 0.f;
    const char* kr = buf + krow * 256;
#pragma unroll
    for (int cs = 0; cs < 8; ++cs) {
      bf16x8 kf = *reinterpret_cast<const bf16x8*>(
          kr + (((cs * 2 + hi) ^ rxk) * 16));
      s = mfma32(kf, qf[cs], s);
    }
  };
  auto ldv = [&](const char* buf, bf16x8 (&vf)[8]) {
    const char* Vt = buf + 16384;
#pragma unroll
    for (int dg = 0; dg < 4; ++dg) {
      const char* vr = Vt + (dg * 32 + c31) * 128;
      vf[2 * dg + 0] = *reinterpret_cast<const bf16x8*>(
          vr + (((wk * 4 + 0 + hi) ^ rxv) * 16));
      vf[2 * dg + 1] = *reinterpret_cast<const bf16x8*>(
          vr + (((wk * 4 + 2 + hi) ^ rxv) * 16));
    }
  };
  auto smpv = [&](f32x16& s, bf16x8 (&vf)[8]) {
#pragma unroll
    for (int r = 0; r < 16; ++r) s[r] = __builtin_amdgcn_exp2f(s[r]);
    {
      float a0 = s[0] + s[1], a1 = s[2] + s[3], a2 = s[4] + s[5], a3 = s[6] + s[7];
      float a4 = s[8] + s[9], a5 = s[10] + s[11], a6 = s[12] + s[13], a7 = s[14] + s[15];
      float b0 = a0 + a1, b1 = a2 + a3, b2 = a4 + a5, b3 = a6 + a7;
      l_run += (b0 + b1) + (b2 + b3);
    }
    unsigned w0 = cvtpk(s[0], s[1]);
    unsigned w1 = cvtpk(s[2], s[3]);
    unsigned w2 = cvtpk(s[4], s[5]);
    unsigned w3 = cvtpk(s[6], s[7]);
    unsigned w4 = cvtpk(s[8], s[9]);
    unsigned w5 = cvtpk(s[10], s[11]);
    unsigned w6 = cvtpk(s[12], s[13]);
    unsigned w7 = cvtpk(s[14], s[15]);
    pswap(w0, w2); pswap(w1, w3); pswap(w4, w6); pswap(w5, w7);
    u32x4 pw0 = {w0, w1, w2, w3};
    u32x4 pw1 = {w4, w5, w6, w7};
    bf16x8 pa0 = __builtin_bit_cast(bf16x8, pw0);
    bf16x8 pa1 = __builtin_bit_cast(bf16x8, pw1);
    __builtin_amdgcn_s_setprio(1);
#pragma unroll
    for (int dg = 0; dg < 4; ++dg) {
      oacc[dg] = mfma32(pa0, vf[2 * dg + 0], oacc[dg]);
      oacc[dg] = mfma32(pa1, vf[2 * dg + 1], oacc[dg]);
    }
    __builtin_amdgcn_s_setprio(0);
  };

  f32x16 sA, sB;
  bf16x8 vfA[8], vfB[8];
  char* const buf0 = lds;
  char* const buf1 = lds + 32768;

  // ---- prologue: stage tile0, then QKT(0); tile1 issued behind the barrier.
#pragma unroll
  for (int i = 0; i < 4; ++i) gload16(K + offK[i], buf0 + kbase + i * 1024);
#pragma unroll
  for (int i = 0; i < 4; ++i) gload16(V + offV[i], buf0 + vbase + i * 1024);
  asm volatile("s_waitcnt vmcnt(0)" ::: "memory");
  __builtin_amdgcn_s_barrier();
  stage_to(buf1);                 // tile 1
  qkt(buf0, sA);
  ldv(buf0, vfA);

  // ---- steady state: bodies kt=1..30 in pairs, then kt=31.
#pragma unroll 1
  for (int base = 1; base < NT - 1; base += 2) {
    // body(odd kt): compute buf1, stage -> buf0
    asm volatile("s_waitcnt vmcnt(0)" ::: "memory");
    __builtin_amdgcn_s_barrier();
    stage_to(buf0);               // tile base+1
    qkt(buf1, sB);
    smpv(sA, vfA);                // overlaps QKT's MFMAs (independent)
    ldv(buf1, vfB);
    // body(even kt): compute buf0, stage -> buf1
    asm volatile("s_waitcnt vmcnt(0)" ::: "memory");
    __builtin_amdgcn_s_barrier();
    stage_to(buf1);               // tile base+2 (max 31)
    qkt(buf0, sA);
    smpv(sB, vfB);
    ldv(buf0, vfA);
  }
  // body(kt=31): compute buf1, no stage
  asm volatile("s_waitcnt vmcnt(0)" ::: "memory");
  __builtin_amdgcn_s_barrier();
  qkt(buf1, sB);
  smpv(sA, vfA);
  ldv(buf1, vfB);
  // drain
  smpv(sB, vfB);

  // ---- split-k-2 merge (wk pairs). Tile buffers dead; reuse LDS.
  __syncthreads();  // all waves done with tile buffers
  l_run += __shfl_xor(l_run, 32);
  float* O1 = (float*)lds;
  float* L1 = (float*)(lds + 32768);
  if (wk == 1) {
#pragma unroll
    for (int dg = 0; dg < 4; ++dg)
#pragma unroll
      for (int r = 0; r < 16; ++r)
        O1[wm * 4096 + (dg * 16 + r) * 64 + l] = oacc[dg][r];
    if (l < 32) L1[wm * 32 + c31] = l_run;
  }
  __syncthreads();
  if (wk == 0) {
    float linv = 1.0f / (l_run + L1[wm * 32 + c31]);
    int ibits = __builtin_bit_cast(int, linv);
#pragma unroll
    for (int dg = 0; dg < 4; ++dg) {
      int h = dg * 32 + c31;
#pragma unroll
      for (int r = 0; r < 16; ++r) {
        int crow = (r & 3) + 8 * (r >> 2) + 4 * hi;
        float fr = __builtin_bit_cast(
            float, __builtin_amdgcn_ds_bpermute(crow * 4, ibits));
        float val = (oacc[dg][r] + O1[wm * 4096 + (dg * 16 + r) * 64 + l]) * fr;
        int n = q0 + wm * 32 + crow;
        O[((size_t)b * NDIM + n) * HDIM + h] = (bf16)val;
      }
    }
  }
}

// ---------------------------------------------------------------------------
// Kernel 3: out = Wf @ O + bf + x (frozen; ~at HBM floor)
// ---------------------------------------------------------------------------
__global__ __launch_bounds__(256) void k3_proj(
    const bf16* __restrict__ O, const float* __restrict__ Wf,
    const float* __restrict__ bfv, const float* __restrict__ x,
    float* __restrict__ out) {
  __shared__ char lds[49152];
  char* Wt = lds;
  char* Ot = lds + 32768;

  const int t = threadIdx.x;
  const int l = t & 63;
  const int w = t >> 6;
  const int b = blockIdx.x >> 5;
  const int n0 = (blockIdx.x & 31) * 64;

#pragma unroll
  for (int pass = 0; pass < 4; ++pass) {
    int n = pass * 16 + (t >> 4);
    int hq = t & 15;
    uint4 d = *reinterpret_cast<const uint4*>(
        O + (size_t)(b * NDIM + n0 + n) * HDIM + hq * 8);
    *reinterpret_cast<uint4*>(Ot + swz256(n, hq * 16)) = d;
  }

#pragma unroll 1
  for (int ch = 0; ch < 2; ++ch) {
    __syncthreads();
#pragma unroll
    for (int pass = 0; pass < 8; ++pass) {
      int cl = pass * 16 + (t >> 4);
      int hq = t & 15;
      const float* src = Wf + (size_t)(ch * 128 + cl) * HDIM + hq * 8;
      float4 v0 = *reinterpret_cast<const float4*>(src);
      float4 v1 = *reinterpret_cast<const float4*>(src + 4);
      *reinterpret_cast<bf16x8*>(Wt + swz256(cl, hq * 16)) = cvt8(v0, v1);
    }
    __syncthreads();

    f32x4 acc[2][4];
#pragma unroll
    for (int i = 0; i < 2; ++i)
#pragma unroll
      for (int j = 0; j < 4; ++j) acc[i][j] = f32x4{0.f, 0.f, 0.f, 0.f};

#pragma unroll
    for (int ks = 0; ks < 4; ++ks) {
      int cb = ks * 64 + (l >> 4) * 16;
      bf16x8 a0 = *reinterpret_cast<const bf16x8*>(
          Wt + swz256(w * 32 + (l & 15), cb));
      bf16x8 a1 = *reinterpret_cast<const bf16x8*>(
          Wt + swz256(w * 32 + 16 + (l & 15), cb));
#pragma unroll
      for (int nf = 0; nf < 4; ++nf) {
        bf16x8 bb = *reinterpret_cast<const bf16x8*>(
            Ot + swz256(nf * 16 + (l & 15), cb));
        acc[0][nf] = mfma16(a0, bb, acc[0][nf]);
        acc[1][nf] = mfma16(a1, bb, acc[1][nf]);
      }
    }

#pragma unroll
    for (int mf = 0; mf < 2; ++mf)
#pragma unroll
      for (int nf = 0; nf < 4; ++nf)
#pragma unroll
        for (int r = 0; r < 4; ++r) {
          int c = ch * 128 + w * 32 + mf * 16 + (l >> 4) * 4 + r;
          int n = n0 + nf * 16 + (l & 15);
          size_t idx = (size_t)(b * CDIM + c) * NDIM + n;
          out[idx] = acc[mf][nf][r] + bfv[c] + x[idx];
        }
  }
}

extern "C" void kernel_launch(void* const* d_in, const int* in_sizes, int n_in,
                              void* d_out, int out_size, void* d_ws,
                              size_t ws_size, hipStream_t stream) {
  (void)in_sizes; (void)n_in;
  const float* x = (const float*)d_in[0];
  const float* Wq = (const float*)d_in[1];
  const float* bq = (const float*)d_in[2];
  const float* Wk = (const float*)d_in[3];
  const float* bk = (const float*)d_in[4];
  const float* Wv = (const float*)d_in[5];
  const float* bv = (const float*)d_in[6];
  const float* Wf = (const float*)d_in[7];
  const float* bfv = (const float*)d_in[8];
  float* out = (float*)d_out;

  if (ws_size < (24u << 20)) return;
  char* ws = (char*)d_ws;
  bf16* Qb = (bf16*)(ws);                  // 8 MB [B][N][H]; reused as O
  bf16* Kb = (bf16*)(ws + (8u << 20));     // 8 MB [B][N][H]
  bf16* Vb = (bf16*)(ws + (16u << 20));    // 8 MB [B][H][N]

  const size_t out_bytes = (size_t)out_size * 4;
  bf16* Wpk = (bf16*)((char*)d_out + out_bytes - 196608);

  const unsigned k2_lds = 65536;
  hipFuncSetAttribute(reinterpret_cast<const void*>(k2_attn),
                      hipFuncAttributeMaxDynamicSharedMemorySize, (int)k2_lds);

  k0_pack<<<48, 256, 0, stream>>>(Wq, Wk, Wv, Wpk);
  k1_qkv<<<512, 256, 0, stream>>>(x, Wpk, bq, bk, bv, Qb, Kb, Vb);
  k2_attn<<<512, 256, k2_lds, stream>>>(Qb, Kb, Vb, Qb);
  k3_proj<<<512, 256, 0, stream>>>(Qb, Wf, bfv, x, out);
}